// Round 12
// baseline (224.259 us; speedup 1.0000x reference)
//
#include <hip/hip_runtime.h>
#include <hip/hip_fp16.h>

#define N_NODES 100000
#define N_EDGES 3200000
#define N_GRAPHS 64
constexpr int NC    = 196;                 // coarse buckets of 512 nodes (196*512=100352)
constexpr int PBLK  = 256;                 // partition blocks
constexpr int CHUNK = N_EDGES / PBLK;      // 12500 edges/block (exact)
constexpr int NBLK  = (N_NODES + 255) / 256;
constexpr int LBLK  = N_NODES / 32;        // 3125 exact: 32 nodes/block, 8 lanes/node
constexpr int FCAP  = 18432;               // k_fine LDS record capacity
#define EPS 1e-5f

typedef float f2 __attribute__((ext_vector_type(2)));
static __device__ __forceinline__ f2 mkf2(float a, float b) { f2 r; r.x = a; r.y = b; return r; }
static __device__ __forceinline__ unsigned h2u(__half2 v) { unsigned r; __builtin_memcpy(&r, &v, 4); return r; }

// ---- workspace layout (bytes) — extents audited, all disjoint ----
// [0x0    ,0x3000 ) zeroed scalars (bns1@0x400, bns2@0x500, bns3@0x700, pooled@0x1000..0x3000)
// [0x4000 ,0x4314 ) cbase          [0x5000,0x5310) btot
// [0x10000,0x71A84) rowptr         [0x80000,0xB1000) histM
// [0x100000,0x1C3500) xp (800KB)   <-- moved out of Ep's tail (bug fix: Ep ends 0x3368000 > old 0x3300000)
// [0x200000,0x1A68000) Es 25.6MB
// [0x1B00000,0x3368000) Ep 25.6MB
// [0x3400000,0x3590000) t1   [0x3800000,0x3B20000) t2   [0x4000000,0x4620000) t3
constexpr size_t OFF_BNS1   = 0x400;
constexpr size_t OFF_BNS2   = 0x500;
constexpr size_t OFF_BNS3   = 0x700;
constexpr size_t OFF_POOLED = 0x1000;
constexpr size_t ZERO_BYTES = 0x3000;
constexpr size_t OFF_CBASE  = 0x4000;
constexpr size_t OFF_BTOT   = 0x5000;
constexpr size_t OFF_ROWPTR = 0x10000;
constexpr size_t OFF_HISTM  = 0x80000;
constexpr size_t OFF_XP     = 0x100000;
constexpr size_t OFF_ES     = 0x200000;
constexpr size_t OFF_EP     = 0x1B00000;
constexpr size_t OFF_T1     = 0x3400000;
constexpr size_t OFF_T2     = 0x3800000;
constexpr size_t OFF_T3     = 0x4000000;

// pad x (fp32 N x 3) -> fp16 N x 4
__global__ __launch_bounds__(256) void xpad_kernel(const float* __restrict__ x,
                                                   __half* __restrict__ xp) {
    int n = blockIdx.x * 256 + threadIdx.x;
    if (n >= N_NODES) return;
    __half2 a = __floats2half2_rn(x[n * 3 + 0], x[n * 3 + 1]);
    __half2 b = __floats2half2_rn(x[n * 3 + 2], 0.f);
    *(uint2*)(xp + (size_t)n * 4) = make_uint2(h2u(a), h2u(b));
}

// per-block LDS coarse-bucket histogram (no global atomics)
__global__ __launch_bounds__(256) void k_hist(const int* __restrict__ dst,
                                              int* __restrict__ histM) {
    __shared__ int h[NC];
    for (int i = threadIdx.x; i < NC; i += 256) h[i] = 0;
    __syncthreads();
    int base = blockIdx.x * CHUNK;
    for (int i = threadIdx.x; i < CHUNK; i += 256)
        atomicAdd(&h[dst[base + i] >> 9], 1);
    __syncthreads();
    for (int i = threadIdx.x; i < NC; i += 256)
        histM[i * PBLK + blockIdx.x] = h[i];
}

// per-bucket exclusive scan over blocks; emit bucket totals
__global__ __launch_bounds__(256) void k_scan1(int* __restrict__ histM,
                                               int* __restrict__ btot) {
    __shared__ int sd[256];
    int b = blockIdx.x, t = threadIdx.x;
    int v = histM[b * PBLK + t];
    sd[t] = v;
    __syncthreads();
    for (int off = 1; off < 256; off <<= 1) {
        int x = (t >= off) ? sd[t - off] : 0;
        __syncthreads();
        sd[t] += x;
        __syncthreads();
    }
    histM[b * PBLK + t] = sd[t] - v;   // exclusive within bucket
    if (t == 255) btot[b] = sd[255];
}

// exclusive scan over bucket totals -> coarse bucket bases
__global__ __launch_bounds__(256) void k_scan2(const int* __restrict__ btot,
                                               int* __restrict__ cbase) {
    __shared__ int sd[256];
    int t = threadIdx.x;
    int v = (t < NC) ? btot[t] : 0;
    sd[t] = v;
    __syncthreads();
    for (int off = 1; off < 256; off <<= 1) {
        int x = (t >= off) ? sd[t - off] : 0;
        __syncthreads();
        sd[t] += x;
        __syncthreads();
    }
    if (t < NC) cbase[t] = sd[t] - v;
    if (t == 0) cbase[NC] = N_EDGES;
}

// partition edges into coarse-bucket sub-streams; record packed to 8B:
// w0 = src(17) | u0q[14:0]<<17 ; w1 = u0q[18:15] | u1q<<4 | dst_low9<<23   (u at 19 bits)
__global__ __launch_bounds__(256) void k_part(const int* __restrict__ src,
                                              const int* __restrict__ dst,
                                              const float2* __restrict__ ea,
                                              const int* __restrict__ histM,
                                              const int* __restrict__ cbase,
                                              uint2* __restrict__ Es) {
    __shared__ int cur[NC];
    for (int i = threadIdx.x; i < NC; i += 256)
        cur[i] = cbase[i] + histM[i * PBLK + blockIdx.x];
    __syncthreads();
    int base = blockIdx.x * CHUNK;
    for (int i = threadIdx.x; i < CHUNK; i += 256) {
        int e = base + i;
        int d = dst[e];
        float2 u = ea[e];
        float u0 = fminf(fmaxf(u.x, 0.f), 1.f);
        float u1 = fminf(fmaxf(u.y, 0.f), 1.f);
        unsigned u0q = __float2uint_rn(u0 * 524287.f);
        unsigned u1q = __float2uint_rn(u1 * 524287.f);
        unsigned w0 = (unsigned)src[e] | ((u0q & 0x7FFFu) << 17);
        unsigned w1 = (u0q >> 15) | (u1q << 4) | ((unsigned)(d & 511) << 23);
        int pos = atomicAdd(&cur[d >> 9], 1);
        Es[pos] = make_uint2(w0, w1);
    }
}

// per coarse bucket: LDS histogram -> scan -> rowptr -> LDS-staged scatter -> coalesced write
__global__ __launch_bounds__(1024) void k_fine(const uint2* __restrict__ Es,
                                               const int* __restrict__ cbase,
                                               int* __restrict__ rowptr,
                                               uint2* __restrict__ Ep) {
    extern __shared__ uint2 rec[];         // FCAP records (144KB dynamic)
    __shared__ int cnt[512];
    __shared__ int cur[512];
    __shared__ int sd[512];
    int b = blockIdx.x, t = threadIdx.x;
    int lo = cbase[b], hi = cbase[b + 1];
    int m = hi - lo;
    if (t < 512) cnt[t] = 0;
    __syncthreads();
    for (int i = lo + t; i < hi; i += 1024)
        atomicAdd(&cnt[Es[i].y >> 23], 1);
    __syncthreads();
    if (t < 512) sd[t] = cnt[t];
    __syncthreads();
    for (int off = 1; off < 512; off <<= 1) {
        int x = (t < 512 && t >= off) ? sd[t - off] : 0;
        __syncthreads();
        if (t < 512) sd[t] += x;
        __syncthreads();
    }
    if (t < 512) {
        int excl = sd[t] - cnt[t];
        cur[t] = excl;                     // bucket-relative
        int n = b * 512 + t;
        if (n < N_NODES) rowptr[n] = lo + excl;
    }
    if (b == NC - 1 && t == 0) rowptr[N_NODES] = N_EDGES;
    __syncthreads();
    if (m <= FCAP) {
        for (int i = lo + t; i < hi; i += 1024) {
            uint2 r = Es[i];
            int pos = atomicAdd(&cur[r.y >> 23], 1);
            rec[pos] = r;
        }
        __syncthreads();
        for (int i = t; i < m; i += 1024)   // coalesced stream-out
            Ep[lo + i] = rec[i];
    } else {
        for (int i = lo + t; i < hi; i += 1024) {
            uint2 r = Es[i];
            int pos = atomicAdd(&cur[r.y >> 23], 1);
            Ep[lo + pos] = r;
        }
    }
}

#define DECODE_EDGE(r)                                              \
    int s = r.x & 0x1FFFF;                                          \
    unsigned u0q = (r.x >> 17) | ((r.y & 0xFu) << 15);              \
    unsigned u1q = (r.y >> 4) & 0x7FFFFu;                           \
    float u0 = u0q * (1.f / 524287.f);                              \
    float u1 = u1q * (1.f / 524287.f);                              \
    float nu0 = 1.f - u0, nu1 = 1.f - u1;                           \
    float b0 = nu0 * nu1, b1 = u0 * nu1, b2 = nu0 * u1, b3 = u0 * u1;

// ---------------- layer 1: CIN=3, COUT=8, fp16-padded in, fp16 out; 8-way edge split ----------------
__global__ __launch_bounds__(256) void layer1_kernel(const __half* __restrict__ xp,
                                                     const int* __restrict__ rowptr,
                                                     const uint2* __restrict__ Ep,
                                                     const float* __restrict__ W,
                                                     __half* __restrict__ tout) {
    __shared__ float Wl[96];               // [k][c][d] flat, same as global
    for (int i = threadIdx.x; i < 96; i += 256) Wl[i] = W[i];
    __syncthreads();
    int lane8 = threadIdx.x & 7;
    int n = blockIdx.x * 32 + (threadIdx.x >> 3);
    int e0 = rowptr[n], e1 = rowptr[n + 1];
    float z[12];
#pragma unroll
    for (int i = 0; i < 12; ++i) z[i] = 0.f;
#pragma unroll 2
    for (int j = e0 + lane8; j < e1; j += 8) {
        uint2 r = Ep[j];
        DECODE_EDGE(r)
        uint2 hv = *(const uint2*)(xp + (size_t)s * 4);
        float2 p0 = __half22float2(*(__half2*)&hv.x);
        float2 p1 = __half22float2(*(__half2*)&hv.y);
        float x0 = p0.x, x1 = p0.y, x2 = p1.x;
        z[0] += b0 * x0; z[1]  += b0 * x1; z[2]  += b0 * x2;
        z[3] += b1 * x0; z[4]  += b1 * x1; z[5]  += b1 * x2;
        z[6] += b2 * x0; z[7]  += b2 * x1; z[8]  += b2 * x2;
        z[9] += b3 * x0; z[10] += b3 * x1; z[11] += b3 * x2;
    }
#pragma unroll
    for (int i = 0; i < 12; ++i) {
        z[i] += __shfl_xor(z[i], 4);
        z[i] += __shfl_xor(z[i], 2);
        z[i] += __shfl_xor(z[i], 1);
    }
    float y = 0.f;
#pragma unroll
    for (int kc = 0; kc < 12; ++kc) y += z[kc] * Wl[kc * 8 + lane8];
    float invd = 1.f / fmaxf((float)(e1 - e0), 1.f);
    float v = y * invd;
    v = v > 0.f ? v : expm1f(v);
    tout[(size_t)n * 8 + lane8] = __float2half_rn(v);
}

// ------- layer 2: CIN=8, COUT=16; fp16 in/out; packed-f32 math; BN folded from sums -------
__global__ __launch_bounds__(256) void layer2_kernel(const __half* __restrict__ xin,
                                                     const float* __restrict__ bns,
                                                     const float* __restrict__ g,
                                                     const float* __restrict__ bb,
                                                     const int* __restrict__ rowptr,
                                                     const uint2* __restrict__ Ep,
                                                     const float* __restrict__ W,
                                                     __half* __restrict__ tout) {
    __shared__ float scA[8], shA[8];
    __shared__ float4 Wl[140];             // f2idx = k*35 + d4p*9 + c   (sc folded)
    __shared__ float shW[64];              // [k][16] = sum_c sh[c]*W[k][c][d]
    int t = threadIdx.x;
    if (t < 8) {
        float mu = bns[t] * (1.f / N_NODES);
        float var = fmaxf(bns[8 + t] * (1.f / N_NODES) - mu * mu, 0.f);
        float s = g[t] * rsqrtf(var + EPS);
        scA[t] = s;
        shA[t] = bb[t] - mu * s;
    }
    __syncthreads();
    if (t < 128) {
        int k = t >> 5, d4 = (t >> 3) & 3, c = t & 7;
        float4 w = ((const float4*)W)[(k * 8 + c) * 4 + d4];
        float s = scA[c];
        Wl[k * 35 + d4 * 9 + c] = make_float4(w.x * s, w.y * s, w.z * s, w.w * s);
    } else if (t < 192) {
        int j = t - 128;
        int k = j >> 4, d = j & 15;
        float acc = 0.f;
#pragma unroll
        for (int c = 0; c < 8; ++c) acc += shA[c] * W[(k * 8 + c) * 16 + d];
        shW[j] = acc;
    }
    __syncthreads();

    int lane8 = t & 7;
    int kq = lane8 & 3, h = lane8 >> 2;
    int ch = kq & 1;                       // c-half
    int eo = lane8 >> 1;                   // edge offset 0..3
    int n = blockIdx.x * 32 + (t >> 3);
    int e0 = rowptr[n], e1 = rowptr[n + 1];
    f2 zf[8];
    float S[4];
#pragma unroll
    for (int i = 0; i < 8; ++i) zf[i] = mkf2(0.f, 0.f);
#pragma unroll
    for (int i = 0; i < 4; ++i) S[i] = 0.f;
#pragma unroll 2
    for (int j = e0 + eo; j < e1; j += 4) {
        uint2 r = Ep[j];
        DECODE_EDGE(r)
        uint2 hv = *(const uint2*)(xin + (size_t)s * 8 + 4 * ch);
        float2 p0 = __half22float2(*(__half2*)&hv.x);
        float2 p1 = __half22float2(*(__half2*)&hv.y);
        f2 x01 = mkf2(p0.x, p0.y), x23 = mkf2(p1.x, p1.y);
        S[0] += b0; S[1] += b1; S[2] += b2; S[3] += b3;
        f2 bbv;
        bbv = mkf2(b0, b0); zf[0] += bbv * x01; zf[1] += bbv * x23;
        bbv = mkf2(b1, b1); zf[2] += bbv * x01; zf[3] += bbv * x23;
        bbv = mkf2(b2, b2); zf[4] += bbv * x01; zf[5] += bbv * x23;
        bbv = mkf2(b3, b3); zf[6] += bbv * x01; zf[7] += bbv * x23;
    }
    // edge-subset reduce (masks 4 then 2)
#pragma unroll
    for (int i = 0; i < 8; ++i) {
        zf[i].x += __shfl_xor(zf[i].x, 4); zf[i].y += __shfl_xor(zf[i].y, 4);
        zf[i].x += __shfl_xor(zf[i].x, 2); zf[i].y += __shfl_xor(zf[i].y, 2);
    }
#pragma unroll
    for (int i = 0; i < 4; ++i) { S[i] += __shfl_xor(S[i], 4); S[i] += __shfl_xor(S[i], 2); }

    // packed y-partial: d-half by h, c-half by ch
    int laneW = 18 * h + 4 * ch;
    f2 ya[2], yb[2];
#pragma unroll
    for (int i = 0; i < 2; ++i) { ya[i] = mkf2(0.f, 0.f); yb[i] = mkf2(0.f, 0.f); }
#pragma unroll
    for (int k = 0; k < 4; ++k) {
        float zs[4] = {zf[2 * k].x, zf[2 * k].y, zf[2 * k + 1].x, zf[2 * k + 1].y};
#pragma unroll
        for (int i = 0; i < 4; ++i) {
            f2 zsp = mkf2(zs[i], zs[i]);
            int base = k * 35 + i + laneW;
#pragma unroll
            for (int d4 = 0; d4 < 2; ++d4) {
                float4 w = Wl[base + 9 * d4];
                ya[d4] += zsp * mkf2(w.x, w.y);
                yb[d4] += zsp * mkf2(w.z, w.w);
            }
        }
    }
    float y[8];
#pragma unroll
    for (int d4 = 0; d4 < 2; ++d4) {
        y[4 * d4 + 0] = ya[d4].x; y[4 * d4 + 1] = ya[d4].y;
        y[4 * d4 + 2] = yb[d4].x; y[4 * d4 + 3] = yb[d4].y;
    }
    // mask-1: sum c-halves, keep d-quarter by ch (static select)
    float y1[4];
#pragma unroll
    for (int i = 0; i < 4; ++i) {
        float a = y[i]     + __shfl_xor(y[i],     1);
        float b = y[4 + i] + __shfl_xor(y[4 + i], 1);
        y1[i] = ch ? b : a;
    }
    int qb = (kq >> 1) & 1;
    float f0 = qb ? y1[2] : y1[0];
    float f1 = qb ? y1[3] : y1[1];
    int d = h * 8 + ch * 4 + qb * 2;
    f0 += S[0] * shW[d]     + S[1] * shW[16 + d]     + S[2] * shW[32 + d]     + S[3] * shW[48 + d];
    f1 += S[0] * shW[d + 1] + S[1] * shW[16 + d + 1] + S[2] * shW[32 + d + 1] + S[3] * shW[48 + d + 1];
    float invd = 1.f / fmaxf((float)(e1 - e0), 1.f);
    f0 *= invd; f1 *= invd;
    f0 = f0 > 0.f ? f0 : expm1f(f0);
    f1 = f1 > 0.f ? f1 : expm1f(f1);
    *(__half2*)(tout + (size_t)n * 16 + d) = __floats2half2_rn(f0, f1);
}

// ------- layer 3: CIN=16, COUT=32; fp16 in/out; packed-f32 math; BN folded from sums -------
__global__ __launch_bounds__(256) void layer3_kernel(const __half* __restrict__ xin,
                                                     const float* __restrict__ bns,
                                                     const float* __restrict__ g,
                                                     const float* __restrict__ bb,
                                                     const int* __restrict__ rowptr,
                                                     const uint2* __restrict__ Ep,
                                                     const float* __restrict__ W,
                                                     __half* __restrict__ tout) {
    __shared__ float scA[16], shA[16];
    __shared__ float4 Wl[580];             // f3 = k*145 + d4p*18 + (d4p>>2) + c + 2*(c>>3)
    __shared__ float shW[128];             // [k][32]
    int t = threadIdx.x;
    if (t < 16) {
        float mu = bns[t] * (1.f / N_NODES);
        float var = fmaxf(bns[16 + t] * (1.f / N_NODES) - mu * mu, 0.f);
        float s = g[t] * rsqrtf(var + EPS);
        scA[t] = s;
        shA[t] = bb[t] - mu * s;
    }
    __syncthreads();
    for (int i = t; i < 512; i += 256) {
        int k = i >> 7, d4 = (i >> 4) & 7, c = i & 15;
        float4 w = ((const float4*)W)[(k * 16 + c) * 8 + d4];
        float s = scA[c];
        Wl[k * 145 + d4 * 18 + (d4 >> 2) + c + 2 * (c >> 3)] =
            make_float4(w.x * s, w.y * s, w.z * s, w.w * s);
    }
    if (t < 128) {
        int k = t >> 5, d = t & 31;
        float acc = 0.f;
#pragma unroll
        for (int c = 0; c < 16; ++c) acc += shA[c] * W[(k * 16 + c) * 32 + d];
        shW[t] = acc;
    }
    __syncthreads();

    int lane8 = t & 7;
    int kq = lane8 & 3, h = lane8 >> 2;
    int n = blockIdx.x * 32 + (t >> 3);
    int e0 = rowptr[n], e1 = rowptr[n + 1];
    f2 zf[8];
    float S[4];
#pragma unroll
    for (int i = 0; i < 8; ++i) zf[i] = mkf2(0.f, 0.f);
#pragma unroll
    for (int i = 0; i < 4; ++i) S[i] = 0.f;
#pragma unroll 2
    for (int j = e0 + h; j < e1; j += 2) {
        uint2 r = Ep[j];
        DECODE_EDGE(r)
        uint2 hv = *(const uint2*)(xin + (size_t)s * 16 + 4 * kq);   // this lane's quarter
        float2 p0 = __half22float2(*(__half2*)&hv.x);
        float2 p1 = __half22float2(*(__half2*)&hv.y);
        f2 x01 = mkf2(p0.x, p0.y), x23 = mkf2(p1.x, p1.y);
        S[0] += b0; S[1] += b1; S[2] += b2; S[3] += b3;
        f2 bbv;
        bbv = mkf2(b0, b0); zf[0] += bbv * x01; zf[1] += bbv * x23;
        bbv = mkf2(b1, b1); zf[2] += bbv * x01; zf[3] += bbv * x23;
        bbv = mkf2(b2, b2); zf[4] += bbv * x01; zf[5] += bbv * x23;
        bbv = mkf2(b3, b3); zf[6] += bbv * x01; zf[7] += bbv * x23;
    }
    // h-reduce (edge halves)
#pragma unroll
    for (int i = 0; i < 8; ++i) {
        zf[i].x += __shfl_xor(zf[i].x, 4);
        zf[i].y += __shfl_xor(zf[i].y, 4);
    }
#pragma unroll
    for (int i = 0; i < 4; ++i) S[i] += __shfl_xor(S[i], 4);

    // packed y-partial: d-half by h, c-quarter by kq  (bank-swizzled W reads)
    int laneW = 4 * kq + 2 * (kq >> 1) + 73 * h;
    f2 ya[4], yb[4];
#pragma unroll
    for (int i = 0; i < 4; ++i) { ya[i] = mkf2(0.f, 0.f); yb[i] = mkf2(0.f, 0.f); }
#pragma unroll
    for (int k = 0; k < 4; ++k) {
        float zs[4] = {zf[2 * k].x, zf[2 * k].y, zf[2 * k + 1].x, zf[2 * k + 1].y};
#pragma unroll
        for (int i = 0; i < 4; ++i) {
            f2 zsp = mkf2(zs[i], zs[i]);
            int base = k * 145 + i + laneW;
#pragma unroll
            for (int d4 = 0; d4 < 4; ++d4) {
                float4 w = Wl[base + 18 * d4];
                ya[d4] += zsp * mkf2(w.x, w.y);
                yb[d4] += zsp * mkf2(w.z, w.w);
            }
        }
    }
    float y[16];
#pragma unroll
    for (int d4 = 0; d4 < 4; ++d4) {
        y[4 * d4 + 0] = ya[d4].x; y[4 * d4 + 1] = ya[d4].y;
        y[4 * d4 + 2] = yb[d4].x; y[4 * d4 + 3] = yb[d4].y;
    }
    // select-tree reduce over c-quarters (masks 1 then 2), static indices
    float y1[8];
#pragma unroll
    for (int i = 0; i < 8; ++i) {
        float a = y[i]     + __shfl_xor(y[i],     1);
        float b = y[8 + i] + __shfl_xor(y[8 + i], 1);
        y1[i] = (kq & 1) ? b : a;
    }
    float y2[4];
#pragma unroll
    for (int i = 0; i < 4; ++i) {
        float a = y1[i]     + __shfl_xor(y1[i],     2);
        float b = y1[4 + i] + __shfl_xor(y1[4 + i], 2);
        y2[i] = (kq & 2) ? b : a;
    }
    int d = h * 16 + (kq & 1) * 8 + ((kq >> 1) & 1) * 4;
#pragma unroll
    for (int i = 0; i < 4; ++i)
        y2[i] += S[0] * shW[d + i] + S[1] * shW[32 + d + i] +
                 S[2] * shW[64 + d + i] + S[3] * shW[96 + d + i];
    float invd = 1.f / fmaxf((float)(e1 - e0), 1.f);
#pragma unroll
    for (int i = 0; i < 4; ++i) {
        float v = y2[i] * invd;
        y2[i] = v > 0.f ? v : expm1f(v);
    }
    __half2 h01 = __floats2half2_rn(y2[0], y2[1]);
    __half2 h23 = __floats2half2_rn(y2[2], y2[3]);
    uint2 st;
    st.x = h2u(h01);
    st.y = h2u(h23);
    *(uint2*)(tout + (size_t)n * 32 + d) = st;
}

// ---------------- BN stats (fp16 input, fp32 sums) ----------------
template <int COUT>
__global__ __launch_bounds__(256) void bnstats_kernel(const __half* __restrict__ t,
                                                      float* __restrict__ sums) {
    constexpr int ROWS = 256 / COUT;
    int ch = threadIdx.x % COUT;
    int r = threadIdx.x / COUT;
    float s = 0.f, q = 0.f;
    for (int n = blockIdx.x * ROWS + r; n < N_NODES; n += gridDim.x * ROWS) {
        float v = __half2float(t[(size_t)n * COUT + ch]);
        s += v;
        q += v * v;
    }
    __shared__ float ls[256], lq[256];
    ls[threadIdx.x] = s; lq[threadIdx.x] = q;
    __syncthreads();
    for (int off = 128; off >= COUT; off >>= 1) {
        if (threadIdx.x < off) {
            ls[threadIdx.x] += ls[threadIdx.x + off];
            lq[threadIdx.x] += lq[threadIdx.x + off];
        }
        __syncthreads();
    }
    if (threadIdx.x < COUT) {
        atomicAdd(&sums[ch], ls[threadIdx.x]);
        atomicAdd(&sums[COUT + ch], lq[threadIdx.x]);
    }
}

// ---------------- pooling (batch is sorted) + FC ----------------
__global__ __launch_bounds__(256) void pool_kernel(const __half* __restrict__ t3,
                                                   const int* __restrict__ batch,
                                                   float* __restrict__ pooled) {
    __shared__ float tile[256][33];
    __shared__ int lb[256];
    int n = blockIdx.x * 256 + threadIdx.x;
    int valid = N_NODES - blockIdx.x * 256;
    if (valid > 256) valid = 256;
    if (n < N_NODES) {
        const uint4* r = (const uint4*)(t3 + (size_t)n * 32);
#pragma unroll
        for (int i = 0; i < 4; ++i) {
            uint4 v = r[i];
            float2 a = __half22float2(*(__half2*)&v.x);
            float2 b = __half22float2(*(__half2*)&v.y);
            float2 c = __half22float2(*(__half2*)&v.z);
            float2 d = __half22float2(*(__half2*)&v.w);
            tile[threadIdx.x][8 * i + 0] = a.x;
            tile[threadIdx.x][8 * i + 1] = a.y;
            tile[threadIdx.x][8 * i + 2] = b.x;
            tile[threadIdx.x][8 * i + 3] = b.y;
            tile[threadIdx.x][8 * i + 4] = c.x;
            tile[threadIdx.x][8 * i + 5] = c.y;
            tile[threadIdx.x][8 * i + 6] = d.x;
            tile[threadIdx.x][8 * i + 7] = d.y;
        }
        lb[threadIdx.x] = batch[n];
    }
    __syncthreads();
    if (threadIdx.x < 32) {
        int ch = threadIdx.x;
        float run = 0.f;
        int gp = lb[0];
        for (int r = 0; r < valid; ++r) {
            int g = lb[r];
            if (g != gp) {
                atomicAdd(&pooled[gp * 32 + ch], run);
                run = 0.f;
                gp = g;
            }
            run += tile[r][ch];
        }
        atomicAdd(&pooled[gp * 32 + ch], run);
    }
}

// final: BN3 fold + mean-pool normalize + FC; per-graph counts via binary search (batch sorted)
__global__ void final_kernel(const float* __restrict__ pooled, const int* __restrict__ batch,
                             const float* __restrict__ bns, const float* __restrict__ g,
                             const float* __restrict__ bb, const float* __restrict__ fcw,
                             float* __restrict__ out) {
    __shared__ float sc3[32], sh3[32];
    __shared__ float rcg[64];
    int t = threadIdx.x;
    if (t < 32) {
        float mu = bns[t] * (1.f / N_NODES);
        float var = fmaxf(bns[32 + t] * (1.f / N_NODES) - mu * mu, 0.f);
        float s = g[t] * rsqrtf(var + EPS);
        sc3[t] = s;
        sh3[t] = bb[t] - mu * s;
    } else if (t >= 64 && t < 128) {
        int gr = t - 64;
        int lo0 = 0, hi0 = N_NODES;
        while (lo0 < hi0) { int m = (lo0 + hi0) >> 1; if (batch[m] < gr) lo0 = m + 1; else hi0 = m; }
        int lo1 = lo0, hi1 = N_NODES;
        while (lo1 < hi1) { int m = (lo1 + hi1) >> 1; if (batch[m] < gr + 1) lo1 = m + 1; else hi1 = m; }
        rcg[gr] = 1.f / fmaxf((float)(lo1 - lo0), 1.f);
    }
    __syncthreads();
    int i = t;
    if (i >= N_GRAPHS * 10) return;
    int gi = i / 10, o = i % 10;
    float rc = rcg[gi];
    float acc = 0.f;
#pragma unroll
    for (int d = 0; d < 32; ++d) {
        float pm = sc3[d] * (pooled[gi * 32 + d] * rc) + sh3[d];
        acc += pm * fcw[o * 32 + d];
    }
    out[i] = acc;
}

extern "C" void kernel_launch(void* const* d_in, const int* in_sizes, int n_in,
                              void* d_out, int out_size, void* d_ws, size_t ws_size,
                              hipStream_t stream) {
    const float* x   = (const float*)d_in[0];
    const int*   ei  = (const int*)d_in[1];
    const float* ea  = (const float*)d_in[2];
    const int*   bat = (const int*)d_in[3];
    const float* W1  = (const float*)d_in[4];
    const float* W2  = (const float*)d_in[5];
    const float* W3  = (const float*)d_in[6];
    const float* g1  = (const float*)d_in[7];
    const float* b1  = (const float*)d_in[8];
    const float* g2  = (const float*)d_in[9];
    const float* b2  = (const float*)d_in[10];
    const float* g3  = (const float*)d_in[11];
    const float* b3  = (const float*)d_in[12];
    const float* fcw = (const float*)d_in[13];
    float* out = (float*)d_out;
    char* ws = (char*)d_ws;

    float*  bns1   = (float*)(ws + OFF_BNS1);
    float*  bns2   = (float*)(ws + OFF_BNS2);
    float*  bns3   = (float*)(ws + OFF_BNS3);
    float*  pooled = (float*)(ws + OFF_POOLED);
    int*    cbase  = (int*)(ws + OFF_CBASE);
    int*    btot   = (int*)(ws + OFF_BTOT);
    int*    rowptr = (int*)(ws + OFF_ROWPTR);
    int*    histM  = (int*)(ws + OFF_HISTM);
    uint2*  Es     = (uint2*)(ws + OFF_ES);
    uint2*  Ep     = (uint2*)(ws + OFF_EP);
    __half* xp     = (__half*)(ws + OFF_XP);
    __half* t1     = (__half*)(ws + OFF_T1);
    __half* t2     = (__half*)(ws + OFF_T2);
    __half* t3     = (__half*)(ws + OFF_T3);

    const int* src = ei;
    const int* dst = ei + N_EDGES;

    // allow >64KB dynamic LDS for k_fine (host-side, idempotent, capture-safe)
    hipFuncSetAttribute((const void*)k_fine,
                        hipFuncAttributeMaxDynamicSharedMemorySize, FCAP * 8);

    hipMemsetAsync(ws, 0, ZERO_BYTES, stream);

    xpad_kernel<<<NBLK, 256, 0, stream>>>(x, xp);
    k_hist<<<PBLK, 256, 0, stream>>>(dst, histM);
    k_scan1<<<NC, 256, 0, stream>>>(histM, btot);
    k_scan2<<<1, 256, 0, stream>>>(btot, cbase);
    k_part<<<PBLK, 256, 0, stream>>>(src, dst, (const float2*)ea, histM, cbase, Es);
    k_fine<<<NC, 1024, FCAP * 8, stream>>>(Es, cbase, rowptr, Ep);

    layer1_kernel<<<LBLK, 256, 0, stream>>>(xp, rowptr, Ep, W1, t1);
    bnstats_kernel<8><<<256, 256, 0, stream>>>(t1, bns1);

    layer2_kernel<<<LBLK, 256, 0, stream>>>(t1, bns1, g1, b1, rowptr, Ep, W2, t2);
    bnstats_kernel<16><<<256, 256, 0, stream>>>(t2, bns2);

    layer3_kernel<<<LBLK, 256, 0, stream>>>(t2, bns2, g2, b2, rowptr, Ep, W3, t3);
    bnstats_kernel<32><<<256, 256, 0, stream>>>(t3, bns3);

    pool_kernel<<<NBLK, 256, 0, stream>>>(t3, bat, pooled);
    final_kernel<<<1, 640, 0, stream>>>(pooled, bat, bns3, g3, b3, fcw, out);
}

// Round 13
// 215.208 us; speedup vs baseline: 1.0421x; 1.0421x over previous
//
#include <hip/hip_runtime.h>
#include <hip/hip_fp16.h>

#define N_NODES 100000
#define N_EDGES 3200000
#define N_GRAPHS 64
constexpr int NC    = 196;                 // coarse buckets of 512 nodes (196*512=100352)
constexpr int PBLK  = 256;                 // partition blocks
constexpr int CHUNK = N_EDGES / PBLK;      // 12500 edges/block (exact)
constexpr int NBLK  = (N_NODES + 255) / 256;
constexpr int LBLK  = N_NODES / 32;        // 3125 exact: 32 nodes/block, 8 lanes/node
constexpr int FCAP  = 18432;               // k_fine LDS record capacity
constexpr int ECAP  = 2048;                // per-layer-block staged edge capacity (mean 1024 + 32 sigma)
#define EPS 1e-5f

typedef float f2 __attribute__((ext_vector_type(2)));
static __device__ __forceinline__ f2 mkf2(float a, float b) { f2 r; r.x = a; r.y = b; return r; }
static __device__ __forceinline__ unsigned h2u(__half2 v) { unsigned r; __builtin_memcpy(&r, &v, 4); return r; }

// ---- workspace layout (bytes) — extents audited, all disjoint ----
// [0x0,0x3000) zeroed scalars | cbase@0x4000 | btot@0x5000 | rowptr@0x10000..0x71A84
// histM@0x80000..0xB1000 | xp@0x100000..0x1C3500 | Es@0x200000..0x1A68000
// Ep@0x1B00000..0x3368000 | t1@0x3400000 | t2@0x3800000 | t3@0x4000000
constexpr size_t OFF_BNS1   = 0x400;
constexpr size_t OFF_BNS2   = 0x500;
constexpr size_t OFF_BNS3   = 0x700;
constexpr size_t OFF_POOLED = 0x1000;
constexpr size_t ZERO_BYTES = 0x3000;
constexpr size_t OFF_CBASE  = 0x4000;
constexpr size_t OFF_BTOT   = 0x5000;
constexpr size_t OFF_ROWPTR = 0x10000;
constexpr size_t OFF_HISTM  = 0x80000;
constexpr size_t OFF_XP     = 0x100000;
constexpr size_t OFF_ES     = 0x200000;
constexpr size_t OFF_EP     = 0x1B00000;
constexpr size_t OFF_T1     = 0x3400000;
constexpr size_t OFF_T2     = 0x3800000;
constexpr size_t OFF_T3     = 0x4000000;

// pad x (fp32 N x 3) -> fp16 N x 4
__global__ __launch_bounds__(256) void xpad_kernel(const float* __restrict__ x,
                                                   __half* __restrict__ xp) {
    int n = blockIdx.x * 256 + threadIdx.x;
    if (n >= N_NODES) return;
    __half2 a = __floats2half2_rn(x[n * 3 + 0], x[n * 3 + 1]);
    __half2 b = __floats2half2_rn(x[n * 3 + 2], 0.f);
    *(uint2*)(xp + (size_t)n * 4) = make_uint2(h2u(a), h2u(b));
}

// per-block LDS coarse-bucket histogram (no global atomics)
__global__ __launch_bounds__(256) void k_hist(const int* __restrict__ dst,
                                              int* __restrict__ histM) {
    __shared__ int h[NC];
    for (int i = threadIdx.x; i < NC; i += 256) h[i] = 0;
    __syncthreads();
    int base = blockIdx.x * CHUNK;
    for (int i = threadIdx.x; i < CHUNK; i += 256)
        atomicAdd(&h[dst[base + i] >> 9], 1);
    __syncthreads();
    for (int i = threadIdx.x; i < NC; i += 256)
        histM[i * PBLK + blockIdx.x] = h[i];
}

// per-bucket exclusive scan over blocks; emit bucket totals
__global__ __launch_bounds__(256) void k_scan1(int* __restrict__ histM,
                                               int* __restrict__ btot) {
    __shared__ int sd[256];
    int b = blockIdx.x, t = threadIdx.x;
    int v = histM[b * PBLK + t];
    sd[t] = v;
    __syncthreads();
    for (int off = 1; off < 256; off <<= 1) {
        int x = (t >= off) ? sd[t - off] : 0;
        __syncthreads();
        sd[t] += x;
        __syncthreads();
    }
    histM[b * PBLK + t] = sd[t] - v;   // exclusive within bucket
    if (t == 255) btot[b] = sd[255];
}

// exclusive scan over bucket totals -> coarse bucket bases
__global__ __launch_bounds__(256) void k_scan2(const int* __restrict__ btot,
                                               int* __restrict__ cbase) {
    __shared__ int sd[256];
    int t = threadIdx.x;
    int v = (t < NC) ? btot[t] : 0;
    sd[t] = v;
    __syncthreads();
    for (int off = 1; off < 256; off <<= 1) {
        int x = (t >= off) ? sd[t - off] : 0;
        __syncthreads();
        sd[t] += x;
        __syncthreads();
    }
    if (t < NC) cbase[t] = sd[t] - v;
    if (t == 0) cbase[NC] = N_EDGES;
}

// partition edges into coarse-bucket sub-streams; record packed to 8B:
// w0 = src(17) | u0q[14:0]<<17 ; w1 = u0q[18:15] | u1q<<4 | dst_low9<<23   (u at 19 bits)
__global__ __launch_bounds__(256) void k_part(const int* __restrict__ src,
                                              const int* __restrict__ dst,
                                              const float2* __restrict__ ea,
                                              const int* __restrict__ histM,
                                              const int* __restrict__ cbase,
                                              uint2* __restrict__ Es) {
    __shared__ int cur[NC];
    for (int i = threadIdx.x; i < NC; i += 256)
        cur[i] = cbase[i] + histM[i * PBLK + blockIdx.x];
    __syncthreads();
    int base = blockIdx.x * CHUNK;
    for (int i = threadIdx.x; i < CHUNK; i += 256) {
        int e = base + i;
        int d = dst[e];
        float2 u = ea[e];
        float u0 = fminf(fmaxf(u.x, 0.f), 1.f);
        float u1 = fminf(fmaxf(u.y, 0.f), 1.f);
        unsigned u0q = __float2uint_rn(u0 * 524287.f);
        unsigned u1q = __float2uint_rn(u1 * 524287.f);
        unsigned w0 = (unsigned)src[e] | ((u0q & 0x7FFFu) << 17);
        unsigned w1 = (u0q >> 15) | (u1q << 4) | ((unsigned)(d & 511) << 23);
        int pos = atomicAdd(&cur[d >> 9], 1);
        Es[pos] = make_uint2(w0, w1);
    }
}

// per coarse bucket: LDS histogram -> scan -> rowptr -> LDS-staged scatter -> coalesced write
__global__ __launch_bounds__(1024) void k_fine(const uint2* __restrict__ Es,
                                               const int* __restrict__ cbase,
                                               int* __restrict__ rowptr,
                                               uint2* __restrict__ Ep) {
    extern __shared__ uint2 rec[];         // FCAP records (144KB dynamic)
    __shared__ int cnt[512];
    __shared__ int cur[512];
    __shared__ int sd[512];
    int b = blockIdx.x, t = threadIdx.x;
    int lo = cbase[b], hi = cbase[b + 1];
    int m = hi - lo;
    if (t < 512) cnt[t] = 0;
    __syncthreads();
    for (int i = lo + t; i < hi; i += 1024)
        atomicAdd(&cnt[Es[i].y >> 23], 1);
    __syncthreads();
    if (t < 512) sd[t] = cnt[t];
    __syncthreads();
    for (int off = 1; off < 512; off <<= 1) {
        int x = (t < 512 && t >= off) ? sd[t - off] : 0;
        __syncthreads();
        if (t < 512) sd[t] += x;
        __syncthreads();
    }
    if (t < 512) {
        int excl = sd[t] - cnt[t];
        cur[t] = excl;                     // bucket-relative
        int n = b * 512 + t;
        if (n < N_NODES) rowptr[n] = lo + excl;
    }
    if (b == NC - 1 && t == 0) rowptr[N_NODES] = N_EDGES;
    __syncthreads();
    if (m <= FCAP) {
        for (int i = lo + t; i < hi; i += 1024) {
            uint2 r = Es[i];
            int pos = atomicAdd(&cur[r.y >> 23], 1);
            rec[pos] = r;
        }
        __syncthreads();
        for (int i = t; i < m; i += 1024)   // coalesced stream-out
            Ep[lo + i] = rec[i];
    } else {
        for (int i = lo + t; i < hi; i += 1024) {
            uint2 r = Es[i];
            int pos = atomicAdd(&cur[r.y >> 23], 1);
            Ep[lo + pos] = r;
        }
    }
}

#define DECODE_EDGE(r)                                              \
    int s = r.x & 0x1FFFF;                                          \
    unsigned u0q = (r.x >> 17) | ((r.y & 0xFu) << 15);              \
    unsigned u1q = (r.y >> 4) & 0x7FFFFu;                           \
    float u0 = u0q * (1.f / 524287.f);                              \
    float u1 = u1q * (1.f / 524287.f);                              \
    float nu0 = 1.f - u0, nu1 = 1.f - u1;                           \
    float b0 = nu0 * nu1, b1 = u0 * nu1, b2 = nu0 * u1, b3 = u0 * u1;

// ---------------- layer 1: CIN=3, COUT=8; LDS-staged Ep; 8-way edge split ----------------
#define L1_BODY                                                     \
        DECODE_EDGE(r)                                              \
        uint2 hv = *(const uint2*)(xp + (size_t)s * 4);             \
        float2 p0 = __half22float2(*(__half2*)&hv.x);               \
        float2 p1 = __half22float2(*(__half2*)&hv.y);               \
        float x0 = p0.x, x1 = p0.y, x2 = p1.x;                      \
        z[0] += b0 * x0; z[1]  += b0 * x1; z[2]  += b0 * x2;        \
        z[3] += b1 * x0; z[4]  += b1 * x1; z[5]  += b1 * x2;        \
        z[6] += b2 * x0; z[7]  += b2 * x1; z[8]  += b2 * x2;        \
        z[9] += b3 * x0; z[10] += b3 * x1; z[11] += b3 * x2;

__global__ __launch_bounds__(256) void layer1_kernel(const __half* __restrict__ xp,
                                                     const int* __restrict__ rowptr,
                                                     const uint2* __restrict__ Ep,
                                                     const float* __restrict__ W,
                                                     __half* __restrict__ tout) {
    __shared__ float Wl[96];               // [k][c][d] flat
    __shared__ uint2 recL[ECAP];
    for (int i = threadIdx.x; i < 96; i += 256) Wl[i] = W[i];
    int nb = blockIdx.x * 32;
    int eb = rowptr[nb], ee = rowptr[nb + 32];
    int mm = ee - eb;
    if (mm <= ECAP)
        for (int i = threadIdx.x; i < mm; i += 256) recL[i] = Ep[eb + i];
    __syncthreads();
    int lane8 = threadIdx.x & 7;
    int n = nb + (threadIdx.x >> 3);
    int e0 = rowptr[n], e1 = rowptr[n + 1];
    float z[12];
#pragma unroll
    for (int i = 0; i < 12; ++i) z[i] = 0.f;
    if (mm <= ECAP) {
#pragma unroll 4
        for (int j = e0 - eb + lane8, je = e1 - eb; j < je; j += 8) {
            uint2 r = recL[j];
            L1_BODY
        }
    } else {
#pragma unroll 2
        for (int j = e0 + lane8; j < e1; j += 8) {
            uint2 r = Ep[j];
            L1_BODY
        }
    }
#pragma unroll
    for (int i = 0; i < 12; ++i) {
        z[i] += __shfl_xor(z[i], 4);
        z[i] += __shfl_xor(z[i], 2);
        z[i] += __shfl_xor(z[i], 1);
    }
    float y = 0.f;
#pragma unroll
    for (int kc = 0; kc < 12; ++kc) y += z[kc] * Wl[kc * 8 + lane8];
    float invd = 1.f / fmaxf((float)(e1 - e0), 1.f);
    float v = y * invd;
    v = v > 0.f ? v : expm1f(v);
    tout[(size_t)n * 8 + lane8] = __float2half_rn(v);
}

// ------- layer 2: CIN=8, COUT=16; LDS-staged Ep; packed-f32; BN folded from sums -------
#define L2_BODY                                                     \
        DECODE_EDGE(r)                                              \
        uint2 hv = *(const uint2*)(xin + (size_t)s * 8 + 4 * ch);   \
        float2 p0 = __half22float2(*(__half2*)&hv.x);               \
        float2 p1 = __half22float2(*(__half2*)&hv.y);               \
        f2 x01 = mkf2(p0.x, p0.y), x23 = mkf2(p1.x, p1.y);          \
        S[0] += b0; S[1] += b1; S[2] += b2; S[3] += b3;             \
        f2 bbv;                                                     \
        bbv = mkf2(b0, b0); zf[0] += bbv * x01; zf[1] += bbv * x23; \
        bbv = mkf2(b1, b1); zf[2] += bbv * x01; zf[3] += bbv * x23; \
        bbv = mkf2(b2, b2); zf[4] += bbv * x01; zf[5] += bbv * x23; \
        bbv = mkf2(b3, b3); zf[6] += bbv * x01; zf[7] += bbv * x23;

__global__ __launch_bounds__(256) void layer2_kernel(const __half* __restrict__ xin,
                                                     const float* __restrict__ bns,
                                                     const float* __restrict__ g,
                                                     const float* __restrict__ bb,
                                                     const int* __restrict__ rowptr,
                                                     const uint2* __restrict__ Ep,
                                                     const float* __restrict__ W,
                                                     __half* __restrict__ tout) {
    __shared__ float scA[8], shA[8];
    __shared__ float4 Wl[140];             // f2idx = k*35 + d4p*9 + c   (sc folded)
    __shared__ float shW[64];              // [k][16]
    __shared__ uint2 recL[ECAP];
    int t = threadIdx.x;
    if (t < 8) {
        float mu = bns[t] * (1.f / N_NODES);
        float var = fmaxf(bns[8 + t] * (1.f / N_NODES) - mu * mu, 0.f);
        float s = g[t] * rsqrtf(var + EPS);
        scA[t] = s;
        shA[t] = bb[t] - mu * s;
    }
    int nb = blockIdx.x * 32;
    int eb = rowptr[nb], ee = rowptr[nb + 32];
    int mm = ee - eb;
    if (mm <= ECAP)
        for (int i = t; i < mm; i += 256) recL[i] = Ep[eb + i];
    __syncthreads();
    if (t < 128) {
        int k = t >> 5, d4 = (t >> 3) & 3, c = t & 7;
        float4 w = ((const float4*)W)[(k * 8 + c) * 4 + d4];
        float s = scA[c];
        Wl[k * 35 + d4 * 9 + c] = make_float4(w.x * s, w.y * s, w.z * s, w.w * s);
    } else if (t < 192) {
        int j = t - 128;
        int k = j >> 4, d = j & 15;
        float acc = 0.f;
#pragma unroll
        for (int c = 0; c < 8; ++c) acc += shA[c] * W[(k * 8 + c) * 16 + d];
        shW[j] = acc;
    }
    __syncthreads();

    int lane8 = t & 7;
    int kq = lane8 & 3, h = lane8 >> 2;
    int ch = kq & 1;                       // c-half
    int eo = lane8 >> 1;                   // edge offset 0..3
    int n = nb + (t >> 3);
    int e0 = rowptr[n], e1 = rowptr[n + 1];
    f2 zf[8];
    float S[4];
#pragma unroll
    for (int i = 0; i < 8; ++i) zf[i] = mkf2(0.f, 0.f);
#pragma unroll
    for (int i = 0; i < 4; ++i) S[i] = 0.f;
    if (mm <= ECAP) {
#pragma unroll 4
        for (int j = e0 - eb + eo, je = e1 - eb; j < je; j += 4) {
            uint2 r = recL[j];
            L2_BODY
        }
    } else {
#pragma unroll 2
        for (int j = e0 + eo; j < e1; j += 4) {
            uint2 r = Ep[j];
            L2_BODY
        }
    }
    // edge-subset reduce (masks 4 then 2)
#pragma unroll
    for (int i = 0; i < 8; ++i) {
        zf[i].x += __shfl_xor(zf[i].x, 4); zf[i].y += __shfl_xor(zf[i].y, 4);
        zf[i].x += __shfl_xor(zf[i].x, 2); zf[i].y += __shfl_xor(zf[i].y, 2);
    }
#pragma unroll
    for (int i = 0; i < 4; ++i) { S[i] += __shfl_xor(S[i], 4); S[i] += __shfl_xor(S[i], 2); }

    // packed y-partial: d-half by h, c-half by ch
    int laneW = 18 * h + 4 * ch;
    f2 ya[2], yb[2];
#pragma unroll
    for (int i = 0; i < 2; ++i) { ya[i] = mkf2(0.f, 0.f); yb[i] = mkf2(0.f, 0.f); }
#pragma unroll
    for (int k = 0; k < 4; ++k) {
        float zs[4] = {zf[2 * k].x, zf[2 * k].y, zf[2 * k + 1].x, zf[2 * k + 1].y};
#pragma unroll
        for (int i = 0; i < 4; ++i) {
            f2 zsp = mkf2(zs[i], zs[i]);
            int base = k * 35 + i + laneW;
#pragma unroll
            for (int d4 = 0; d4 < 2; ++d4) {
                float4 w = Wl[base + 9 * d4];
                ya[d4] += zsp * mkf2(w.x, w.y);
                yb[d4] += zsp * mkf2(w.z, w.w);
            }
        }
    }
    float y[8];
#pragma unroll
    for (int d4 = 0; d4 < 2; ++d4) {
        y[4 * d4 + 0] = ya[d4].x; y[4 * d4 + 1] = ya[d4].y;
        y[4 * d4 + 2] = yb[d4].x; y[4 * d4 + 3] = yb[d4].y;
    }
    // mask-1: sum c-halves, keep d-quarter by ch (static select)
    float y1[4];
#pragma unroll
    for (int i = 0; i < 4; ++i) {
        float a = y[i]     + __shfl_xor(y[i],     1);
        float b = y[4 + i] + __shfl_xor(y[4 + i], 1);
        y1[i] = ch ? b : a;
    }
    int qb = (kq >> 1) & 1;
    float f0 = qb ? y1[2] : y1[0];
    float f1 = qb ? y1[3] : y1[1];
    int d = h * 8 + ch * 4 + qb * 2;
    f0 += S[0] * shW[d]     + S[1] * shW[16 + d]     + S[2] * shW[32 + d]     + S[3] * shW[48 + d];
    f1 += S[0] * shW[d + 1] + S[1] * shW[16 + d + 1] + S[2] * shW[32 + d + 1] + S[3] * shW[48 + d + 1];
    float invd = 1.f / fmaxf((float)(e1 - e0), 1.f);
    f0 *= invd; f1 *= invd;
    f0 = f0 > 0.f ? f0 : expm1f(f0);
    f1 = f1 > 0.f ? f1 : expm1f(f1);
    *(__half2*)(tout + (size_t)n * 16 + d) = __floats2half2_rn(f0, f1);
}

// ------- layer 3: CIN=16, COUT=32; LDS-staged Ep; packed-f32; BN folded from sums -------
#define L3_BODY                                                     \
        DECODE_EDGE(r)                                              \
        uint2 hv = *(const uint2*)(xin + (size_t)s * 16 + 4 * kq);  \
        float2 p0 = __half22float2(*(__half2*)&hv.x);               \
        float2 p1 = __half22float2(*(__half2*)&hv.y);               \
        f2 x01 = mkf2(p0.x, p0.y), x23 = mkf2(p1.x, p1.y);          \
        S[0] += b0; S[1] += b1; S[2] += b2; S[3] += b3;             \
        f2 bbv;                                                     \
        bbv = mkf2(b0, b0); zf[0] += bbv * x01; zf[1] += bbv * x23; \
        bbv = mkf2(b1, b1); zf[2] += bbv * x01; zf[3] += bbv * x23; \
        bbv = mkf2(b2, b2); zf[4] += bbv * x01; zf[5] += bbv * x23; \
        bbv = mkf2(b3, b3); zf[6] += bbv * x01; zf[7] += bbv * x23;

__global__ __launch_bounds__(256) void layer3_kernel(const __half* __restrict__ xin,
                                                     const float* __restrict__ bns,
                                                     const float* __restrict__ g,
                                                     const float* __restrict__ bb,
                                                     const int* __restrict__ rowptr,
                                                     const uint2* __restrict__ Ep,
                                                     const float* __restrict__ W,
                                                     __half* __restrict__ tout) {
    __shared__ float scA[16], shA[16];
    __shared__ float4 Wl[580];             // f3 = k*145 + d4p*18 + (d4p>>2) + c + 2*(c>>3)
    __shared__ float shW[128];             // [k][32]
    __shared__ uint2 recL[ECAP];
    int t = threadIdx.x;
    if (t < 16) {
        float mu = bns[t] * (1.f / N_NODES);
        float var = fmaxf(bns[16 + t] * (1.f / N_NODES) - mu * mu, 0.f);
        float s = g[t] * rsqrtf(var + EPS);
        scA[t] = s;
        shA[t] = bb[t] - mu * s;
    }
    int nb = blockIdx.x * 32;
    int eb = rowptr[nb], ee = rowptr[nb + 32];
    int mm = ee - eb;
    if (mm <= ECAP)
        for (int i = t; i < mm; i += 256) recL[i] = Ep[eb + i];
    __syncthreads();
    for (int i = t; i < 512; i += 256) {
        int k = i >> 7, d4 = (i >> 4) & 7, c = i & 15;
        float4 w = ((const float4*)W)[(k * 16 + c) * 8 + d4];
        float s = scA[c];
        Wl[k * 145 + d4 * 18 + (d4 >> 2) + c + 2 * (c >> 3)] =
            make_float4(w.x * s, w.y * s, w.z * s, w.w * s);
    }
    if (t < 128) {
        int k = t >> 5, d = t & 31;
        float acc = 0.f;
#pragma unroll
        for (int c = 0; c < 16; ++c) acc += shA[c] * W[(k * 16 + c) * 32 + d];
        shW[t] = acc;
    }
    __syncthreads();

    int lane8 = t & 7;
    int kq = lane8 & 3, h = lane8 >> 2;
    int n = nb + (t >> 3);
    int e0 = rowptr[n], e1 = rowptr[n + 1];
    f2 zf[8];
    float S[4];
#pragma unroll
    for (int i = 0; i < 8; ++i) zf[i] = mkf2(0.f, 0.f);
#pragma unroll
    for (int i = 0; i < 4; ++i) S[i] = 0.f;
    if (mm <= ECAP) {
#pragma unroll 4
        for (int j = e0 - eb + h, je = e1 - eb; j < je; j += 2) {
            uint2 r = recL[j];
            L3_BODY
        }
    } else {
#pragma unroll 2
        for (int j = e0 + h; j < e1; j += 2) {
            uint2 r = Ep[j];
            L3_BODY
        }
    }
    // h-reduce (edge halves)
#pragma unroll
    for (int i = 0; i < 8; ++i) {
        zf[i].x += __shfl_xor(zf[i].x, 4);
        zf[i].y += __shfl_xor(zf[i].y, 4);
    }
#pragma unroll
    for (int i = 0; i < 4; ++i) S[i] += __shfl_xor(S[i], 4);

    // packed y-partial: d-half by h, c-quarter by kq  (bank-swizzled W reads)
    int laneW = 4 * kq + 2 * (kq >> 1) + 73 * h;
    f2 ya[4], yb[4];
#pragma unroll
    for (int i = 0; i < 4; ++i) { ya[i] = mkf2(0.f, 0.f); yb[i] = mkf2(0.f, 0.f); }
#pragma unroll
    for (int k = 0; k < 4; ++k) {
        float zs[4] = {zf[2 * k].x, zf[2 * k].y, zf[2 * k + 1].x, zf[2 * k + 1].y};
#pragma unroll
        for (int i = 0; i < 4; ++i) {
            f2 zsp = mkf2(zs[i], zs[i]);
            int base = k * 145 + i + laneW;
#pragma unroll
            for (int d4 = 0; d4 < 4; ++d4) {
                float4 w = Wl[base + 18 * d4];
                ya[d4] += zsp * mkf2(w.x, w.y);
                yb[d4] += zsp * mkf2(w.z, w.w);
            }
        }
    }
    float y[16];
#pragma unroll
    for (int d4 = 0; d4 < 4; ++d4) {
        y[4 * d4 + 0] = ya[d4].x; y[4 * d4 + 1] = ya[d4].y;
        y[4 * d4 + 2] = yb[d4].x; y[4 * d4 + 3] = yb[d4].y;
    }
    // select-tree reduce over c-quarters (masks 1 then 2), static indices
    float y1[8];
#pragma unroll
    for (int i = 0; i < 8; ++i) {
        float a = y[i]     + __shfl_xor(y[i],     1);
        float b = y[8 + i] + __shfl_xor(y[8 + i], 1);
        y1[i] = (kq & 1) ? b : a;
    }
    float y2[4];
#pragma unroll
    for (int i = 0; i < 4; ++i) {
        float a = y1[i]     + __shfl_xor(y1[i],     2);
        float b = y1[4 + i] + __shfl_xor(y1[4 + i], 2);
        y2[i] = (kq & 2) ? b : a;
    }
    int d = h * 16 + (kq & 1) * 8 + ((kq >> 1) & 1) * 4;
#pragma unroll
    for (int i = 0; i < 4; ++i)
        y2[i] += S[0] * shW[d + i] + S[1] * shW[32 + d + i] +
                 S[2] * shW[64 + d + i] + S[3] * shW[96 + d + i];
    float invd = 1.f / fmaxf((float)(e1 - e0), 1.f);
#pragma unroll
    for (int i = 0; i < 4; ++i) {
        float v = y2[i] * invd;
        y2[i] = v > 0.f ? v : expm1f(v);
    }
    __half2 h01 = __floats2half2_rn(y2[0], y2[1]);
    __half2 h23 = __floats2half2_rn(y2[2], y2[3]);
    uint2 st;
    st.x = h2u(h01);
    st.y = h2u(h23);
    *(uint2*)(tout + (size_t)n * 32 + d) = st;
}

// ---------------- BN stats (fp16 input, fp32 sums) ----------------
template <int COUT>
__global__ __launch_bounds__(256) void bnstats_kernel(const __half* __restrict__ t,
                                                      float* __restrict__ sums) {
    constexpr int ROWS = 256 / COUT;
    int ch = threadIdx.x % COUT;
    int r = threadIdx.x / COUT;
    float s = 0.f, q = 0.f;
    for (int n = blockIdx.x * ROWS + r; n < N_NODES; n += gridDim.x * ROWS) {
        float v = __half2float(t[(size_t)n * COUT + ch]);
        s += v;
        q += v * v;
    }
    __shared__ float ls[256], lq[256];
    ls[threadIdx.x] = s; lq[threadIdx.x] = q;
    __syncthreads();
    for (int off = 128; off >= COUT; off >>= 1) {
        if (threadIdx.x < off) {
            ls[threadIdx.x] += ls[threadIdx.x + off];
            lq[threadIdx.x] += lq[threadIdx.x + off];
        }
        __syncthreads();
    }
    if (threadIdx.x < COUT) {
        atomicAdd(&sums[ch], ls[threadIdx.x]);
        atomicAdd(&sums[COUT + ch], lq[threadIdx.x]);
    }
}

// ---------------- pooling (batch is sorted) + FC ----------------
__global__ __launch_bounds__(256) void pool_kernel(const __half* __restrict__ t3,
                                                   const int* __restrict__ batch,
                                                   float* __restrict__ pooled) {
    __shared__ float tile[256][33];
    __shared__ int lb[256];
    int n = blockIdx.x * 256 + threadIdx.x;
    int valid = N_NODES - blockIdx.x * 256;
    if (valid > 256) valid = 256;
    if (n < N_NODES) {
        const uint4* r = (const uint4*)(t3 + (size_t)n * 32);
#pragma unroll
        for (int i = 0; i < 4; ++i) {
            uint4 v = r[i];
            float2 a = __half22float2(*(__half2*)&v.x);
            float2 b = __half22float2(*(__half2*)&v.y);
            float2 c = __half22float2(*(__half2*)&v.z);
            float2 d = __half22float2(*(__half2*)&v.w);
            tile[threadIdx.x][8 * i + 0] = a.x;
            tile[threadIdx.x][8 * i + 1] = a.y;
            tile[threadIdx.x][8 * i + 2] = b.x;
            tile[threadIdx.x][8 * i + 3] = b.y;
            tile[threadIdx.x][8 * i + 4] = c.x;
            tile[threadIdx.x][8 * i + 5] = c.y;
            tile[threadIdx.x][8 * i + 6] = d.x;
            tile[threadIdx.x][8 * i + 7] = d.y;
        }
        lb[threadIdx.x] = batch[n];
    }
    __syncthreads();
    if (threadIdx.x < 32) {
        int ch = threadIdx.x;
        float run = 0.f;
        int gp = lb[0];
        for (int r = 0; r < valid; ++r) {
            int g = lb[r];
            if (g != gp) {
                atomicAdd(&pooled[gp * 32 + ch], run);
                run = 0.f;
                gp = g;
            }
            run += tile[r][ch];
        }
        atomicAdd(&pooled[gp * 32 + ch], run);
    }
}

// final: BN3 fold + mean-pool normalize + FC; per-graph counts via binary search (batch sorted)
__global__ void final_kernel(const float* __restrict__ pooled, const int* __restrict__ batch,
                             const float* __restrict__ bns, const float* __restrict__ g,
                             const float* __restrict__ bb, const float* __restrict__ fcw,
                             float* __restrict__ out) {
    __shared__ float sc3[32], sh3[32];
    __shared__ float rcg[64];
    int t = threadIdx.x;
    if (t < 32) {
        float mu = bns[t] * (1.f / N_NODES);
        float var = fmaxf(bns[32 + t] * (1.f / N_NODES) - mu * mu, 0.f);
        float s = g[t] * rsqrtf(var + EPS);
        sc3[t] = s;
        sh3[t] = bb[t] - mu * s;
    } else if (t >= 64 && t < 128) {
        int gr = t - 64;
        int lo0 = 0, hi0 = N_NODES;
        while (lo0 < hi0) { int m = (lo0 + hi0) >> 1; if (batch[m] < gr) lo0 = m + 1; else hi0 = m; }
        int lo1 = lo0, hi1 = N_NODES;
        while (lo1 < hi1) { int m = (lo1 + hi1) >> 1; if (batch[m] < gr + 1) lo1 = m + 1; else hi1 = m; }
        rcg[gr] = 1.f / fmaxf((float)(lo1 - lo0), 1.f);
    }
    __syncthreads();
    int i = t;
    if (i >= N_GRAPHS * 10) return;
    int gi = i / 10, o = i % 10;
    float rc = rcg[gi];
    float acc = 0.f;
#pragma unroll
    for (int d = 0; d < 32; ++d) {
        float pm = sc3[d] * (pooled[gi * 32 + d] * rc) + sh3[d];
        acc += pm * fcw[o * 32 + d];
    }
    out[i] = acc;
}

extern "C" void kernel_launch(void* const* d_in, const int* in_sizes, int n_in,
                              void* d_out, int out_size, void* d_ws, size_t ws_size,
                              hipStream_t stream) {
    const float* x   = (const float*)d_in[0];
    const int*   ei  = (const int*)d_in[1];
    const float* ea  = (const float*)d_in[2];
    const int*   bat = (const int*)d_in[3];
    const float* W1  = (const float*)d_in[4];
    const float* W2  = (const float*)d_in[5];
    const float* W3  = (const float*)d_in[6];
    const float* g1  = (const float*)d_in[7];
    const float* b1  = (const float*)d_in[8];
    const float* g2  = (const float*)d_in[9];
    const float* b2  = (const float*)d_in[10];
    const float* g3  = (const float*)d_in[11];
    const float* b3  = (const float*)d_in[12];
    const float* fcw = (const float*)d_in[13];
    float* out = (float*)d_out;
    char* ws = (char*)d_ws;

    float*  bns1   = (float*)(ws + OFF_BNS1);
    float*  bns2   = (float*)(ws + OFF_BNS2);
    float*  bns3   = (float*)(ws + OFF_BNS3);
    float*  pooled = (float*)(ws + OFF_POOLED);
    int*    cbase  = (int*)(ws + OFF_CBASE);
    int*    btot   = (int*)(ws + OFF_BTOT);
    int*    rowptr = (int*)(ws + OFF_ROWPTR);
    int*    histM  = (int*)(ws + OFF_HISTM);
    uint2*  Es     = (uint2*)(ws + OFF_ES);
    uint2*  Ep     = (uint2*)(ws + OFF_EP);
    __half* xp     = (__half*)(ws + OFF_XP);
    __half* t1     = (__half*)(ws + OFF_T1);
    __half* t2     = (__half*)(ws + OFF_T2);
    __half* t3     = (__half*)(ws + OFF_T3);

    const int* src = ei;
    const int* dst = ei + N_EDGES;

    // allow >64KB dynamic LDS for k_fine (host-side, idempotent, capture-safe)
    hipFuncSetAttribute((const void*)k_fine,
                        hipFuncAttributeMaxDynamicSharedMemorySize, FCAP * 8);

    hipMemsetAsync(ws, 0, ZERO_BYTES, stream);

    xpad_kernel<<<NBLK, 256, 0, stream>>>(x, xp);
    k_hist<<<PBLK, 256, 0, stream>>>(dst, histM);
    k_scan1<<<NC, 256, 0, stream>>>(histM, btot);
    k_scan2<<<1, 256, 0, stream>>>(btot, cbase);
    k_part<<<PBLK, 256, 0, stream>>>(src, dst, (const float2*)ea, histM, cbase, Es);
    k_fine<<<NC, 1024, FCAP * 8, stream>>>(Es, cbase, rowptr, Ep);

    layer1_kernel<<<LBLK, 256, 0, stream>>>(xp, rowptr, Ep, W1, t1);
    bnstats_kernel<8><<<256, 256, 0, stream>>>(t1, bns1);

    layer2_kernel<<<LBLK, 256, 0, stream>>>(t1, bns1, g1, b1, rowptr, Ep, W2, t2);
    bnstats_kernel<16><<<256, 256, 0, stream>>>(t2, bns2);

    layer3_kernel<<<LBLK, 256, 0, stream>>>(t2, bns2, g2, b2, rowptr, Ep, W3, t3);
    bnstats_kernel<32><<<256, 256, 0, stream>>>(t3, bns3);

    pool_kernel<<<NBLK, 256, 0, stream>>>(t3, bat, pooled);
    final_kernel<<<1, 640, 0, stream>>>(pooled, bat, bns3, g3, b3, fcw, out);
}

// Round 14
// 203.070 us; speedup vs baseline: 1.1043x; 1.0598x over previous
//
#include <hip/hip_runtime.h>
#include <hip/hip_fp16.h>

#define N_NODES 100000
#define N_EDGES 3200000
#define N_GRAPHS 64
constexpr int NC    = 196;                 // coarse buckets of 512 nodes (196*512=100352)
constexpr int PBLK  = 256;                 // partition blocks (1 per CU)
constexpr int CHUNK = N_EDGES / PBLK;      // 12500 edges/block (exact)
constexpr int NBLK  = (N_NODES + 255) / 256;
constexpr int LBLK  = N_NODES / 32;        // 3125 exact: 32 nodes/block, 8 lanes/node
constexpr int FCAP  = 18432;               // k_fine LDS record capacity
constexpr int ECAP  = 2048;                // per-layer-block staged edge capacity
#define EPS 1e-5f

typedef float f2 __attribute__((ext_vector_type(2)));
static __device__ __forceinline__ f2 mkf2(float a, float b) { f2 r; r.x = a; r.y = b; return r; }
static __device__ __forceinline__ unsigned h2u(__half2 v) { unsigned r; __builtin_memcpy(&r, &v, 4); return r; }

// ---- workspace layout (bytes) — extents audited, all disjoint ----
// [0x0,0x3000) zeroed scalars | cbase@0x4000 | btot@0x5000 | rowptr@0x10000..0x71A84
// histM@0x80000..0xB1000 | xp@0x100000..0x1C3500 | Es@0x200000..0x1A68000
// Ep@0x1B00000..0x3368000 | t1@0x3400000 | t2@0x3800000 | t3@0x4000000
constexpr size_t OFF_BNS1   = 0x400;
constexpr size_t OFF_BNS2   = 0x500;
constexpr size_t OFF_BNS3   = 0x700;
constexpr size_t OFF_POOLED = 0x1000;
constexpr size_t ZERO_BYTES = 0x3000;
constexpr size_t OFF_CBASE  = 0x4000;
constexpr size_t OFF_BTOT   = 0x5000;
constexpr size_t OFF_ROWPTR = 0x10000;
constexpr size_t OFF_HISTM  = 0x80000;
constexpr size_t OFF_XP     = 0x100000;
constexpr size_t OFF_ES     = 0x200000;
constexpr size_t OFF_EP     = 0x1B00000;
constexpr size_t OFF_T1     = 0x3400000;
constexpr size_t OFF_T2     = 0x3800000;
constexpr size_t OFF_T3     = 0x4000000;

// pad x (fp32 N x 3) -> fp16 N x 4
__global__ __launch_bounds__(256) void xpad_kernel(const float* __restrict__ x,
                                                   __half* __restrict__ xp) {
    int n = blockIdx.x * 256 + threadIdx.x;
    if (n >= N_NODES) return;
    __half2 a = __floats2half2_rn(x[n * 3 + 0], x[n * 3 + 1]);
    __half2 b = __floats2half2_rn(x[n * 3 + 2], 0.f);
    *(uint2*)(xp + (size_t)n * 4) = make_uint2(h2u(a), h2u(b));
}

// per-block LDS coarse-bucket histogram (no global atomics); 1024 thr for latency hiding
__global__ __launch_bounds__(1024) void k_hist(const int* __restrict__ dst,
                                               int* __restrict__ histM) {
    __shared__ int h[NC];
    for (int i = threadIdx.x; i < NC; i += 1024) h[i] = 0;
    __syncthreads();
    int base = blockIdx.x * CHUNK;
    for (int i = threadIdx.x; i < CHUNK; i += 1024)
        atomicAdd(&h[dst[base + i] >> 9], 1);
    __syncthreads();
    for (int i = threadIdx.x; i < NC; i += 1024)
        histM[i * PBLK + blockIdx.x] = h[i];
}

// per-bucket exclusive scan over blocks; emit bucket totals
__global__ __launch_bounds__(256) void k_scan1(int* __restrict__ histM,
                                               int* __restrict__ btot) {
    __shared__ int sd[256];
    int b = blockIdx.x, t = threadIdx.x;
    int v = histM[b * PBLK + t];
    sd[t] = v;
    __syncthreads();
    for (int off = 1; off < 256; off <<= 1) {
        int x = (t >= off) ? sd[t - off] : 0;
        __syncthreads();
        sd[t] += x;
        __syncthreads();
    }
    histM[b * PBLK + t] = sd[t] - v;   // exclusive within bucket
    if (t == 255) btot[b] = sd[255];
}

// exclusive scan over bucket totals -> coarse bucket bases
__global__ __launch_bounds__(256) void k_scan2(const int* __restrict__ btot,
                                               int* __restrict__ cbase) {
    __shared__ int sd[256];
    int t = threadIdx.x;
    int v = (t < NC) ? btot[t] : 0;
    sd[t] = v;
    __syncthreads();
    for (int off = 1; off < 256; off <<= 1) {
        int x = (t >= off) ? sd[t - off] : 0;
        __syncthreads();
        sd[t] += x;
        __syncthreads();
    }
    if (t < NC) cbase[t] = sd[t] - v;
    if (t == 0) cbase[NC] = N_EDGES;
}

// partition edges into coarse-bucket sub-streams; 1024 thr; record packed to 8B:
// w0 = src(17) | u0q[14:0]<<17 ; w1 = u0q[18:15] | u1q<<4 | dst_low9<<23   (u at 19 bits)
__global__ __launch_bounds__(1024) void k_part(const int* __restrict__ src,
                                               const int* __restrict__ dst,
                                               const float2* __restrict__ ea,
                                               const int* __restrict__ histM,
                                               const int* __restrict__ cbase,
                                               uint2* __restrict__ Es) {
    __shared__ int cur[NC];
    for (int i = threadIdx.x; i < NC; i += 1024)
        cur[i] = cbase[i] + histM[i * PBLK + blockIdx.x];
    __syncthreads();
    int base = blockIdx.x * CHUNK;
    for (int i = threadIdx.x; i < CHUNK; i += 1024) {
        int e = base + i;
        int d = dst[e];
        float2 u = ea[e];
        float u0 = fminf(fmaxf(u.x, 0.f), 1.f);
        float u1 = fminf(fmaxf(u.y, 0.f), 1.f);
        unsigned u0q = __float2uint_rn(u0 * 524287.f);
        unsigned u1q = __float2uint_rn(u1 * 524287.f);
        unsigned w0 = (unsigned)src[e] | ((u0q & 0x7FFFu) << 17);
        unsigned w1 = (u0q >> 15) | (u1q << 4) | ((unsigned)(d & 511) << 23);
        int pos = atomicAdd(&cur[d >> 9], 1);
        Es[pos] = make_uint2(w0, w1);
    }
}

// per coarse bucket: LDS histogram -> scan -> rowptr -> LDS-staged scatter -> coalesced write
__global__ __launch_bounds__(1024) void k_fine(const uint2* __restrict__ Es,
                                               const int* __restrict__ cbase,
                                               int* __restrict__ rowptr,
                                               uint2* __restrict__ Ep) {
    extern __shared__ uint2 rec[];         // FCAP records (144KB dynamic)
    __shared__ int cnt[512];
    __shared__ int cur[512];
    __shared__ int sd[512];
    int b = blockIdx.x, t = threadIdx.x;
    int lo = cbase[b], hi = cbase[b + 1];
    int m = hi - lo;
    if (t < 512) cnt[t] = 0;
    __syncthreads();
    for (int i = lo + t; i < hi; i += 1024)
        atomicAdd(&cnt[Es[i].y >> 23], 1);
    __syncthreads();
    if (t < 512) sd[t] = cnt[t];
    __syncthreads();
    for (int off = 1; off < 512; off <<= 1) {
        int x = (t < 512 && t >= off) ? sd[t - off] : 0;
        __syncthreads();
        if (t < 512) sd[t] += x;
        __syncthreads();
    }
    if (t < 512) {
        int excl = sd[t] - cnt[t];
        cur[t] = excl;                     // bucket-relative
        int n = b * 512 + t;
        if (n < N_NODES) rowptr[n] = lo + excl;
    }
    if (b == NC - 1 && t == 0) rowptr[N_NODES] = N_EDGES;
    __syncthreads();
    if (m <= FCAP) {
        for (int i = lo + t; i < hi; i += 1024) {
            uint2 r = Es[i];
            int pos = atomicAdd(&cur[r.y >> 23], 1);
            rec[pos] = r;
        }
        __syncthreads();
        for (int i = t; i < m; i += 1024)   // coalesced stream-out
            Ep[lo + i] = rec[i];
    } else {
        for (int i = lo + t; i < hi; i += 1024) {
            uint2 r = Es[i];
            int pos = atomicAdd(&cur[r.y >> 23], 1);
            Ep[lo + pos] = r;
        }
    }
}

#define DECODE_EDGE(r)                                              \
    int s = r.x & 0x1FFFF;                                          \
    unsigned u0q = (r.x >> 17) | ((r.y & 0xFu) << 15);              \
    unsigned u1q = (r.y >> 4) & 0x7FFFFu;                           \
    float u0 = u0q * (1.f / 524287.f);                              \
    float u1 = u1q * (1.f / 524287.f);                              \
    float nu0 = 1.f - u0, nu1 = 1.f - u1;                           \
    float b0 = nu0 * nu1, b1 = u0 * nu1, b2 = nu0 * u1, b3 = u0 * u1;

// ---------------- layer 1: CIN=3, COUT=8; LDS-staged Ep; 8-way edge split ----------------
#define L1_BODY                                                     \
        DECODE_EDGE(r)                                              \
        uint2 hv = *(const uint2*)(xp + (size_t)s * 4);             \
        float2 p0 = __half22float2(*(__half2*)&hv.x);               \
        float2 p1 = __half22float2(*(__half2*)&hv.y);               \
        float x0 = p0.x, x1 = p0.y, x2 = p1.x;                      \
        z[0] += b0 * x0; z[1]  += b0 * x1; z[2]  += b0 * x2;        \
        z[3] += b1 * x0; z[4]  += b1 * x1; z[5]  += b1 * x2;        \
        z[6] += b2 * x0; z[7]  += b2 * x1; z[8]  += b2 * x2;        \
        z[9] += b3 * x0; z[10] += b3 * x1; z[11] += b3 * x2;

__global__ __launch_bounds__(256) void layer1_kernel(const __half* __restrict__ xp,
                                                     const int* __restrict__ rowptr,
                                                     const uint2* __restrict__ Ep,
                                                     const float* __restrict__ W,
                                                     __half* __restrict__ tout) {
    __shared__ float Wl[96];               // [k][c][d] flat
    __shared__ uint2 recL[ECAP];
    for (int i = threadIdx.x; i < 96; i += 256) Wl[i] = W[i];
    int nb = blockIdx.x * 32;
    int eb = rowptr[nb], ee = rowptr[nb + 32];
    int mm = ee - eb;
    if (mm <= ECAP)
        for (int i = threadIdx.x; i < mm; i += 256) recL[i] = Ep[eb + i];
    __syncthreads();
    int lane8 = threadIdx.x & 7;
    int n = nb + (threadIdx.x >> 3);
    int e0 = rowptr[n], e1 = rowptr[n + 1];
    float z[12];
#pragma unroll
    for (int i = 0; i < 12; ++i) z[i] = 0.f;
    if (mm <= ECAP) {
#pragma unroll 4
        for (int j = e0 - eb + lane8, je = e1 - eb; j < je; j += 8) {
            uint2 r = recL[j];
            L1_BODY
        }
    } else {
#pragma unroll 2
        for (int j = e0 + lane8; j < e1; j += 8) {
            uint2 r = Ep[j];
            L1_BODY
        }
    }
#pragma unroll
    for (int i = 0; i < 12; ++i) {
        z[i] += __shfl_xor(z[i], 4);
        z[i] += __shfl_xor(z[i], 2);
        z[i] += __shfl_xor(z[i], 1);
    }
    float y = 0.f;
#pragma unroll
    for (int kc = 0; kc < 12; ++kc) y += z[kc] * Wl[kc * 8 + lane8];
    float invd = 1.f / fmaxf((float)(e1 - e0), 1.f);
    float v = y * invd;
    v = v > 0.f ? v : expm1f(v);
    tout[(size_t)n * 8 + lane8] = __float2half_rn(v);
}

// ------- layer 2: CIN=8, COUT=16; LDS-staged Ep; packed-f32; BN folded from sums -------
#define L2_BODY                                                     \
        DECODE_EDGE(r)                                              \
        uint2 hv = *(const uint2*)(xin + (size_t)s * 8 + 4 * ch);   \
        float2 p0 = __half22float2(*(__half2*)&hv.x);               \
        float2 p1 = __half22float2(*(__half2*)&hv.y);               \
        f2 x01 = mkf2(p0.x, p0.y), x23 = mkf2(p1.x, p1.y);          \
        S[0] += b0; S[1] += b1; S[2] += b2; S[3] += b3;             \
        f2 bbv;                                                     \
        bbv = mkf2(b0, b0); zf[0] += bbv * x01; zf[1] += bbv * x23; \
        bbv = mkf2(b1, b1); zf[2] += bbv * x01; zf[3] += bbv * x23; \
        bbv = mkf2(b2, b2); zf[4] += bbv * x01; zf[5] += bbv * x23; \
        bbv = mkf2(b3, b3); zf[6] += bbv * x01; zf[7] += bbv * x23;

__global__ __launch_bounds__(256) void layer2_kernel(const __half* __restrict__ xin,
                                                     const float* __restrict__ bns,
                                                     const float* __restrict__ g,
                                                     const float* __restrict__ bb,
                                                     const int* __restrict__ rowptr,
                                                     const uint2* __restrict__ Ep,
                                                     const float* __restrict__ W,
                                                     __half* __restrict__ tout) {
    __shared__ float scA[8], shA[8];
    __shared__ float4 Wl[140];             // f2idx = k*35 + d4p*9 + c   (sc folded)
    __shared__ float shW[64];              // [k][16]
    __shared__ uint2 recL[ECAP];
    int t = threadIdx.x;
    if (t < 8) {
        float mu = bns[t] * (1.f / N_NODES);
        float var = fmaxf(bns[8 + t] * (1.f / N_NODES) - mu * mu, 0.f);
        float s = g[t] * rsqrtf(var + EPS);
        scA[t] = s;
        shA[t] = bb[t] - mu * s;
    }
    int nb = blockIdx.x * 32;
    int eb = rowptr[nb], ee = rowptr[nb + 32];
    int mm = ee - eb;
    if (mm <= ECAP)
        for (int i = t; i < mm; i += 256) recL[i] = Ep[eb + i];
    __syncthreads();
    if (t < 128) {
        int k = t >> 5, d4 = (t >> 3) & 3, c = t & 7;
        float4 w = ((const float4*)W)[(k * 8 + c) * 4 + d4];
        float s = scA[c];
        Wl[k * 35 + d4 * 9 + c] = make_float4(w.x * s, w.y * s, w.z * s, w.w * s);
    } else if (t < 192) {
        int j = t - 128;
        int k = j >> 4, d = j & 15;
        float acc = 0.f;
#pragma unroll
        for (int c = 0; c < 8; ++c) acc += shA[c] * W[(k * 8 + c) * 16 + d];
        shW[j] = acc;
    }
    __syncthreads();

    int lane8 = t & 7;
    int kq = lane8 & 3, h = lane8 >> 2;
    int ch = kq & 1;                       // c-half
    int eo = lane8 >> 1;                   // edge offset 0..3
    int n = nb + (t >> 3);
    int e0 = rowptr[n], e1 = rowptr[n + 1];
    f2 zf[8];
    float S[4];
#pragma unroll
    for (int i = 0; i < 8; ++i) zf[i] = mkf2(0.f, 0.f);
#pragma unroll
    for (int i = 0; i < 4; ++i) S[i] = 0.f;
    if (mm <= ECAP) {
#pragma unroll 4
        for (int j = e0 - eb + eo, je = e1 - eb; j < je; j += 4) {
            uint2 r = recL[j];
            L2_BODY
        }
    } else {
#pragma unroll 2
        for (int j = e0 + eo; j < e1; j += 4) {
            uint2 r = Ep[j];
            L2_BODY
        }
    }
    // edge-subset reduce (masks 4 then 2)
#pragma unroll
    for (int i = 0; i < 8; ++i) {
        zf[i].x += __shfl_xor(zf[i].x, 4); zf[i].y += __shfl_xor(zf[i].y, 4);
        zf[i].x += __shfl_xor(zf[i].x, 2); zf[i].y += __shfl_xor(zf[i].y, 2);
    }
#pragma unroll
    for (int i = 0; i < 4; ++i) { S[i] += __shfl_xor(S[i], 4); S[i] += __shfl_xor(S[i], 2); }

    // packed y-partial: d-half by h, c-half by ch
    int laneW = 18 * h + 4 * ch;
    f2 ya[2], yb[2];
#pragma unroll
    for (int i = 0; i < 2; ++i) { ya[i] = mkf2(0.f, 0.f); yb[i] = mkf2(0.f, 0.f); }
#pragma unroll
    for (int k = 0; k < 4; ++k) {
        float zs[4] = {zf[2 * k].x, zf[2 * k].y, zf[2 * k + 1].x, zf[2 * k + 1].y};
#pragma unroll
        for (int i = 0; i < 4; ++i) {
            f2 zsp = mkf2(zs[i], zs[i]);
            int base = k * 35 + i + laneW;
#pragma unroll
            for (int d4 = 0; d4 < 2; ++d4) {
                float4 w = Wl[base + 9 * d4];
                ya[d4] += zsp * mkf2(w.x, w.y);
                yb[d4] += zsp * mkf2(w.z, w.w);
            }
        }
    }
    float y[8];
#pragma unroll
    for (int d4 = 0; d4 < 2; ++d4) {
        y[4 * d4 + 0] = ya[d4].x; y[4 * d4 + 1] = ya[d4].y;
        y[4 * d4 + 2] = yb[d4].x; y[4 * d4 + 3] = yb[d4].y;
    }
    // mask-1: sum c-halves, keep d-quarter by ch (static select)
    float y1[4];
#pragma unroll
    for (int i = 0; i < 4; ++i) {
        float a = y[i]     + __shfl_xor(y[i],     1);
        float b = y[4 + i] + __shfl_xor(y[4 + i], 1);
        y1[i] = ch ? b : a;
    }
    int qb = (kq >> 1) & 1;
    float f0 = qb ? y1[2] : y1[0];
    float f1 = qb ? y1[3] : y1[1];
    int d = h * 8 + ch * 4 + qb * 2;
    f0 += S[0] * shW[d]     + S[1] * shW[16 + d]     + S[2] * shW[32 + d]     + S[3] * shW[48 + d];
    f1 += S[0] * shW[d + 1] + S[1] * shW[16 + d + 1] + S[2] * shW[32 + d + 1] + S[3] * shW[48 + d + 1];
    float invd = 1.f / fmaxf((float)(e1 - e0), 1.f);
    f0 *= invd; f1 *= invd;
    f0 = f0 > 0.f ? f0 : expm1f(f0);
    f1 = f1 > 0.f ? f1 : expm1f(f1);
    *(__half2*)(tout + (size_t)n * 16 + d) = __floats2half2_rn(f0, f1);
}

// ------- layer 3: CIN=16, COUT=32; LDS-staged Ep; packed-f32; BN folded from sums -------
#define L3_BODY                                                     \
        DECODE_EDGE(r)                                              \
        uint2 hv = *(const uint2*)(xin + (size_t)s * 16 + 4 * kq);  \
        float2 p0 = __half22float2(*(__half2*)&hv.x);               \
        float2 p1 = __half22float2(*(__half2*)&hv.y);               \
        f2 x01 = mkf2(p0.x, p0.y), x23 = mkf2(p1.x, p1.y);          \
        S[0] += b0; S[1] += b1; S[2] += b2; S[3] += b3;             \
        f2 bbv;                                                     \
        bbv = mkf2(b0, b0); zf[0] += bbv * x01; zf[1] += bbv * x23; \
        bbv = mkf2(b1, b1); zf[2] += bbv * x01; zf[3] += bbv * x23; \
        bbv = mkf2(b2, b2); zf[4] += bbv * x01; zf[5] += bbv * x23; \
        bbv = mkf2(b3, b3); zf[6] += bbv * x01; zf[7] += bbv * x23;

__global__ __launch_bounds__(256) void layer3_kernel(const __half* __restrict__ xin,
                                                     const float* __restrict__ bns,
                                                     const float* __restrict__ g,
                                                     const float* __restrict__ bb,
                                                     const int* __restrict__ rowptr,
                                                     const uint2* __restrict__ Ep,
                                                     const float* __restrict__ W,
                                                     __half* __restrict__ tout) {
    __shared__ float scA[16], shA[16];
    __shared__ float4 Wl[580];             // f3 = k*145 + d4p*18 + (d4p>>2) + c + 2*(c>>3)
    __shared__ float shW[128];             // [k][32]
    __shared__ uint2 recL[ECAP];
    int t = threadIdx.x;
    if (t < 16) {
        float mu = bns[t] * (1.f / N_NODES);
        float var = fmaxf(bns[16 + t] * (1.f / N_NODES) - mu * mu, 0.f);
        float s = g[t] * rsqrtf(var + EPS);
        scA[t] = s;
        shA[t] = bb[t] - mu * s;
    }
    int nb = blockIdx.x * 32;
    int eb = rowptr[nb], ee = rowptr[nb + 32];
    int mm = ee - eb;
    if (mm <= ECAP)
        for (int i = t; i < mm; i += 256) recL[i] = Ep[eb + i];
    __syncthreads();
    for (int i = t; i < 512; i += 256) {
        int k = i >> 7, d4 = (i >> 4) & 7, c = i & 15;
        float4 w = ((const float4*)W)[(k * 16 + c) * 8 + d4];
        float s = scA[c];
        Wl[k * 145 + d4 * 18 + (d4 >> 2) + c + 2 * (c >> 3)] =
            make_float4(w.x * s, w.y * s, w.z * s, w.w * s);
    }
    if (t < 128) {
        int k = t >> 5, d = t & 31;
        float acc = 0.f;
#pragma unroll
        for (int c = 0; c < 16; ++c) acc += shA[c] * W[(k * 16 + c) * 32 + d];
        shW[t] = acc;
    }
    __syncthreads();

    int lane8 = t & 7;
    int kq = lane8 & 3, h = lane8 >> 2;
    int n = nb + (t >> 3);
    int e0 = rowptr[n], e1 = rowptr[n + 1];
    f2 zf[8];
    float S[4];
#pragma unroll
    for (int i = 0; i < 8; ++i) zf[i] = mkf2(0.f, 0.f);
#pragma unroll
    for (int i = 0; i < 4; ++i) S[i] = 0.f;
    if (mm <= ECAP) {
#pragma unroll 4
        for (int j = e0 - eb + h, je = e1 - eb; j < je; j += 2) {
            uint2 r = recL[j];
            L3_BODY
        }
    } else {
#pragma unroll 2
        for (int j = e0 + h; j < e1; j += 2) {
            uint2 r = Ep[j];
            L3_BODY
        }
    }
    // h-reduce (edge halves)
#pragma unroll
    for (int i = 0; i < 8; ++i) {
        zf[i].x += __shfl_xor(zf[i].x, 4);
        zf[i].y += __shfl_xor(zf[i].y, 4);
    }
#pragma unroll
    for (int i = 0; i < 4; ++i) S[i] += __shfl_xor(S[i], 4);

    // packed y-partial: d-half by h, c-quarter by kq  (bank-swizzled W reads)
    int laneW = 4 * kq + 2 * (kq >> 1) + 73 * h;
    f2 ya[4], yb[4];
#pragma unroll
    for (int i = 0; i < 4; ++i) { ya[i] = mkf2(0.f, 0.f); yb[i] = mkf2(0.f, 0.f); }
#pragma unroll
    for (int k = 0; k < 4; ++k) {
        float zs[4] = {zf[2 * k].x, zf[2 * k].y, zf[2 * k + 1].x, zf[2 * k + 1].y};
#pragma unroll
        for (int i = 0; i < 4; ++i) {
            f2 zsp = mkf2(zs[i], zs[i]);
            int base = k * 145 + i + laneW;
#pragma unroll
            for (int d4 = 0; d4 < 4; ++d4) {
                float4 w = Wl[base + 18 * d4];
                ya[d4] += zsp * mkf2(w.x, w.y);
                yb[d4] += zsp * mkf2(w.z, w.w);
            }
        }
    }
    float y[16];
#pragma unroll
    for (int d4 = 0; d4 < 4; ++d4) {
        y[4 * d4 + 0] = ya[d4].x; y[4 * d4 + 1] = ya[d4].y;
        y[4 * d4 + 2] = yb[d4].x; y[4 * d4 + 3] = yb[d4].y;
    }
    // select-tree reduce over c-quarters (masks 1 then 2), static indices
    float y1[8];
#pragma unroll
    for (int i = 0; i < 8; ++i) {
        float a = y[i]     + __shfl_xor(y[i],     1);
        float b = y[8 + i] + __shfl_xor(y[8 + i], 1);
        y1[i] = (kq & 1) ? b : a;
    }
    float y2[4];
#pragma unroll
    for (int i = 0; i < 4; ++i) {
        float a = y1[i]     + __shfl_xor(y1[i],     2);
        float b = y1[4 + i] + __shfl_xor(y1[4 + i], 2);
        y2[i] = (kq & 2) ? b : a;
    }
    int d = h * 16 + (kq & 1) * 8 + ((kq >> 1) & 1) * 4;
#pragma unroll
    for (int i = 0; i < 4; ++i)
        y2[i] += S[0] * shW[d + i] + S[1] * shW[32 + d + i] +
                 S[2] * shW[64 + d + i] + S[3] * shW[96 + d + i];
    float invd = 1.f / fmaxf((float)(e1 - e0), 1.f);
#pragma unroll
    for (int i = 0; i < 4; ++i) {
        float v = y2[i] * invd;
        y2[i] = v > 0.f ? v : expm1f(v);
    }
    __half2 h01 = __floats2half2_rn(y2[0], y2[1]);
    __half2 h23 = __floats2half2_rn(y2[2], y2[3]);
    uint2 st;
    st.x = h2u(h01);
    st.y = h2u(h23);
    *(uint2*)(tout + (size_t)n * 32 + d) = st;
}

// ---------------- BN stats (fp16 input, fp32 sums) ----------------
template <int COUT>
__global__ __launch_bounds__(256) void bnstats_kernel(const __half* __restrict__ t,
                                                      float* __restrict__ sums) {
    constexpr int ROWS = 256 / COUT;
    int ch = threadIdx.x % COUT;
    int r = threadIdx.x / COUT;
    float s = 0.f, q = 0.f;
    for (int n = blockIdx.x * ROWS + r; n < N_NODES; n += gridDim.x * ROWS) {
        float v = __half2float(t[(size_t)n * COUT + ch]);
        s += v;
        q += v * v;
    }
    __shared__ float ls[256], lq[256];
    ls[threadIdx.x] = s; lq[threadIdx.x] = q;
    __syncthreads();
    for (int off = 128; off >= COUT; off >>= 1) {
        if (threadIdx.x < off) {
            ls[threadIdx.x] += ls[threadIdx.x + off];
            lq[threadIdx.x] += lq[threadIdx.x + off];
        }
        __syncthreads();
    }
    if (threadIdx.x < COUT) {
        atomicAdd(&sums[ch], ls[threadIdx.x]);
        atomicAdd(&sums[COUT + ch], lq[threadIdx.x]);
    }
}

// ---------------- pooling (batch is sorted) + FC ----------------
__global__ __launch_bounds__(256) void pool_kernel(const __half* __restrict__ t3,
                                                   const int* __restrict__ batch,
                                                   float* __restrict__ pooled) {
    __shared__ float tile[256][33];
    __shared__ int lb[256];
    int n = blockIdx.x * 256 + threadIdx.x;
    int valid = N_NODES - blockIdx.x * 256;
    if (valid > 256) valid = 256;
    if (n < N_NODES) {
        const uint4* r = (const uint4*)(t3 + (size_t)n * 32);
#pragma unroll
        for (int i = 0; i < 4; ++i) {
            uint4 v = r[i];
            float2 a = __half22float2(*(__half2*)&v.x);
            float2 b = __half22float2(*(__half2*)&v.y);
            float2 c = __half22float2(*(__half2*)&v.z);
            float2 d = __half22float2(*(__half2*)&v.w);
            tile[threadIdx.x][8 * i + 0] = a.x;
            tile[threadIdx.x][8 * i + 1] = a.y;
            tile[threadIdx.x][8 * i + 2] = b.x;
            tile[threadIdx.x][8 * i + 3] = b.y;
            tile[threadIdx.x][8 * i + 4] = c.x;
            tile[threadIdx.x][8 * i + 5] = c.y;
            tile[threadIdx.x][8 * i + 6] = d.x;
            tile[threadIdx.x][8 * i + 7] = d.y;
        }
        lb[threadIdx.x] = batch[n];
    }
    __syncthreads();
    if (threadIdx.x < 32) {
        int ch = threadIdx.x;
        float run = 0.f;
        int gp = lb[0];
        for (int r = 0; r < valid; ++r) {
            int g = lb[r];
            if (g != gp) {
                atomicAdd(&pooled[gp * 32 + ch], run);
                run = 0.f;
                gp = g;
            }
            run += tile[r][ch];
        }
        atomicAdd(&pooled[gp * 32 + ch], run);
    }
}

// final: BN3 fold + mean-pool normalize + FC; per-graph counts via binary search (batch sorted)
__global__ void final_kernel(const float* __restrict__ pooled, const int* __restrict__ batch,
                             const float* __restrict__ bns, const float* __restrict__ g,
                             const float* __restrict__ bb, const float* __restrict__ fcw,
                             float* __restrict__ out) {
    __shared__ float sc3[32], sh3[32];
    __shared__ float rcg[64];
    int t = threadIdx.x;
    if (t < 32) {
        float mu = bns[t] * (1.f / N_NODES);
        float var = fmaxf(bns[32 + t] * (1.f / N_NODES) - mu * mu, 0.f);
        float s = g[t] * rsqrtf(var + EPS);
        sc3[t] = s;
        sh3[t] = bb[t] - mu * s;
    } else if (t >= 64 && t < 128) {
        int gr = t - 64;
        int lo0 = 0, hi0 = N_NODES;
        while (lo0 < hi0) { int m = (lo0 + hi0) >> 1; if (batch[m] < gr) lo0 = m + 1; else hi0 = m; }
        int lo1 = lo0, hi1 = N_NODES;
        while (lo1 < hi1) { int m = (lo1 + hi1) >> 1; if (batch[m] < gr + 1) lo1 = m + 1; else hi1 = m; }
        rcg[gr] = 1.f / fmaxf((float)(lo1 - lo0), 1.f);
    }
    __syncthreads();
    int i = t;
    if (i >= N_GRAPHS * 10) return;
    int gi = i / 10, o = i % 10;
    float rc = rcg[gi];
    float acc = 0.f;
#pragma unroll
    for (int d = 0; d < 32; ++d) {
        float pm = sc3[d] * (pooled[gi * 32 + d] * rc) + sh3[d];
        acc += pm * fcw[o * 32 + d];
    }
    out[i] = acc;
}

extern "C" void kernel_launch(void* const* d_in, const int* in_sizes, int n_in,
                              void* d_out, int out_size, void* d_ws, size_t ws_size,
                              hipStream_t stream) {
    const float* x   = (const float*)d_in[0];
    const int*   ei  = (const int*)d_in[1];
    const float* ea  = (const float*)d_in[2];
    const int*   bat = (const int*)d_in[3];
    const float* W1  = (const float*)d_in[4];
    const float* W2  = (const float*)d_in[5];
    const float* W3  = (const float*)d_in[6];
    const float* g1  = (const float*)d_in[7];
    const float* b1  = (const float*)d_in[8];
    const float* g2  = (const float*)d_in[9];
    const float* b2  = (const float*)d_in[10];
    const float* g3  = (const float*)d_in[11];
    const float* b3  = (const float*)d_in[12];
    const float* fcw = (const float*)d_in[13];
    float* out = (float*)d_out;
    char* ws = (char*)d_ws;

    float*  bns1   = (float*)(ws + OFF_BNS1);
    float*  bns2   = (float*)(ws + OFF_BNS2);
    float*  bns3   = (float*)(ws + OFF_BNS3);
    float*  pooled = (float*)(ws + OFF_POOLED);
    int*    cbase  = (int*)(ws + OFF_CBASE);
    int*    btot   = (int*)(ws + OFF_BTOT);
    int*    rowptr = (int*)(ws + OFF_ROWPTR);
    int*    histM  = (int*)(ws + OFF_HISTM);
    uint2*  Es     = (uint2*)(ws + OFF_ES);
    uint2*  Ep     = (uint2*)(ws + OFF_EP);
    __half* xp     = (__half*)(ws + OFF_XP);
    __half* t1     = (__half*)(ws + OFF_T1);
    __half* t2     = (__half*)(ws + OFF_T2);
    __half* t3     = (__half*)(ws + OFF_T3);

    const int* src = ei;
    const int* dst = ei + N_EDGES;

    // allow >64KB dynamic LDS for k_fine (host-side, idempotent, capture-safe)
    hipFuncSetAttribute((const void*)k_fine,
                        hipFuncAttributeMaxDynamicSharedMemorySize, FCAP * 8);

    hipMemsetAsync(ws, 0, ZERO_BYTES, stream);

    xpad_kernel<<<NBLK, 256, 0, stream>>>(x, xp);
    k_hist<<<PBLK, 1024, 0, stream>>>(dst, histM);
    k_scan1<<<NC, 256, 0, stream>>>(histM, btot);
    k_scan2<<<1, 256, 0, stream>>>(btot, cbase);
    k_part<<<PBLK, 1024, 0, stream>>>(src, dst, (const float2*)ea, histM, cbase, Es);
    k_fine<<<NC, 1024, FCAP * 8, stream>>>(Es, cbase, rowptr, Ep);

    layer1_kernel<<<LBLK, 256, 0, stream>>>(xp, rowptr, Ep, W1, t1);
    bnstats_kernel<8><<<256, 256, 0, stream>>>(t1, bns1);

    layer2_kernel<<<LBLK, 256, 0, stream>>>(t1, bns1, g1, b1, rowptr, Ep, W2, t2);
    bnstats_kernel<16><<<256, 256, 0, stream>>>(t2, bns2);

    layer3_kernel<<<LBLK, 256, 0, stream>>>(t2, bns2, g2, b2, rowptr, Ep, W3, t3);
    bnstats_kernel<32><<<256, 256, 0, stream>>>(t3, bns3);

    pool_kernel<<<NBLK, 256, 0, stream>>>(t3, bat, pooled);
    final_kernel<<<1, 640, 0, stream>>>(pooled, bat, bns3, g3, b3, fcw, out);
}

// Round 15
// 197.065 us; speedup vs baseline: 1.1380x; 1.0305x over previous
//
#include <hip/hip_runtime.h>
#include <hip/hip_fp16.h>

#define N_NODES 100000
#define N_EDGES 3200000
#define N_GRAPHS 64
constexpr int NC    = 196;                 // coarse buckets of 512 nodes (196*512=100352)
constexpr int PBLK  = 256;                 // partition blocks (1 per CU)
constexpr int CHUNK = N_EDGES / PBLK;      // 12500 edges/block (exact)
constexpr int NBLK  = (N_NODES + 255) / 256;
constexpr int LBLK  = N_NODES / 32;        // 3125 exact: 32 nodes/block, 8 lanes/node
constexpr int FCAP  = 18432;               // k_fine LDS record capacity
constexpr int ECAP  = 2048;                // per-layer-block staged edge capacity
#define EPS 1e-5f

typedef float f2 __attribute__((ext_vector_type(2)));
static __device__ __forceinline__ f2 mkf2(float a, float b) { f2 r; r.x = a; r.y = b; return r; }
static __device__ __forceinline__ unsigned h2u(__half2 v) { unsigned r; __builtin_memcpy(&r, &v, 4); return r; }

// ---- workspace layout (bytes) — extents audited, all disjoint ----
constexpr size_t OFF_BNS1   = 0x400;
constexpr size_t OFF_BNS2   = 0x500;
constexpr size_t OFF_BNS3   = 0x700;
constexpr size_t OFF_POOLED = 0x1000;
constexpr size_t ZERO_BYTES = 0x3000;
constexpr size_t OFF_CBASE  = 0x4000;
constexpr size_t OFF_BTOT   = 0x5000;
constexpr size_t OFF_ROWPTR = 0x10000;
constexpr size_t OFF_HISTM  = 0x80000;
constexpr size_t OFF_XP     = 0x100000;
constexpr size_t OFF_ES     = 0x200000;
constexpr size_t OFF_EP     = 0x1B00000;
constexpr size_t OFF_T1     = 0x3400000;
constexpr size_t OFF_T2     = 0x3800000;
constexpr size_t OFF_T3     = 0x4000000;

// pad x (fp32 N x 3) -> fp16 N x 4
__global__ __launch_bounds__(256) void xpad_kernel(const float* __restrict__ x,
                                                   __half* __restrict__ xp) {
    int n = blockIdx.x * 256 + threadIdx.x;
    if (n >= N_NODES) return;
    __half2 a = __floats2half2_rn(x[n * 3 + 0], x[n * 3 + 1]);
    __half2 b = __floats2half2_rn(x[n * 3 + 2], 0.f);
    *(uint2*)(xp + (size_t)n * 4) = make_uint2(h2u(a), h2u(b));
}

// per-block LDS coarse-bucket histogram (no global atomics)
__global__ __launch_bounds__(1024) void k_hist(const int* __restrict__ dst,
                                               int* __restrict__ histM) {
    __shared__ int h[NC];
    for (int i = threadIdx.x; i < NC; i += 1024) h[i] = 0;
    __syncthreads();
    int base = blockIdx.x * CHUNK;
    for (int i = threadIdx.x; i < CHUNK; i += 1024)
        atomicAdd(&h[dst[base + i] >> 9], 1);
    __syncthreads();
    for (int i = threadIdx.x; i < NC; i += 1024)
        histM[i * PBLK + blockIdx.x] = h[i];
}

// per-bucket exclusive scan over blocks; emit bucket totals
__global__ __launch_bounds__(256) void k_scan1(int* __restrict__ histM,
                                               int* __restrict__ btot) {
    __shared__ int sd[256];
    int b = blockIdx.x, t = threadIdx.x;
    int v = histM[b * PBLK + t];
    sd[t] = v;
    __syncthreads();
    for (int off = 1; off < 256; off <<= 1) {
        int x = (t >= off) ? sd[t - off] : 0;
        __syncthreads();
        sd[t] += x;
        __syncthreads();
    }
    histM[b * PBLK + t] = sd[t] - v;   // exclusive within bucket
    if (t == 255) btot[b] = sd[255];
}

// exclusive scan over bucket totals -> coarse bucket bases
__global__ __launch_bounds__(256) void k_scan2(const int* __restrict__ btot,
                                               int* __restrict__ cbase) {
    __shared__ int sd[256];
    int t = threadIdx.x;
    int v = (t < NC) ? btot[t] : 0;
    sd[t] = v;
    __syncthreads();
    for (int off = 1; off < 256; off <<= 1) {
        int x = (t >= off) ? sd[t - off] : 0;
        __syncthreads();
        sd[t] += x;
        __syncthreads();
    }
    if (t < NC) cbase[t] = sd[t] - v;
    if (t == 0) cbase[NC] = N_EDGES;
}

// partition: LDS counting-sort of the block's 12500-edge chunk by coarse bucket,
// then per-bucket runs streamed out COALESCED (no scattered global stores).
// record: w0 = src(17) | u0q[14:0]<<17 ; w1 = u0q[18:15] | u1q<<4 | dst_low9<<23
__global__ __launch_bounds__(1024) void k_part(const int* __restrict__ src,
                                               const int* __restrict__ dst,
                                               const float2* __restrict__ ea,
                                               const int* __restrict__ histM,
                                               const int* __restrict__ cbase,
                                               uint2* __restrict__ Es) {
    extern __shared__ uint2 rec[];         // CHUNK records (100KB dynamic)
    __shared__ int cnt[NC];
    __shared__ int cur[NC];
    __shared__ int lst[NC];
    __shared__ int gof[NC];
    __shared__ int sd[256];
    int t = threadIdx.x, b = blockIdx.x;
    for (int i = t; i < NC; i += 1024) cnt[i] = 0;
    __syncthreads();
    int base = b * CHUNK;
    for (int i = t; i < CHUNK; i += 1024)
        atomicAdd(&cnt[dst[base + i] >> 9], 1);
    __syncthreads();
    // exclusive scan of cnt[0..NC) using threads 0..255 (all threads hit barriers)
    int v = 0;
    if (t < 256) { v = (t < NC) ? cnt[t] : 0; sd[t] = v; }
    __syncthreads();
    for (int off = 1; off < 256; off <<= 1) {
        int x = 0;
        if (t < 256 && t >= off) x = sd[t - off];
        __syncthreads();
        if (t < 256) sd[t] += x;
        __syncthreads();
    }
    if (t < NC) {
        int excl = sd[t] - v;
        cur[t] = excl;
        lst[t] = excl;
        gof[t] = cbase[t] + histM[t * PBLK + b];
    }
    __syncthreads();
    // pack + scatter into LDS at sorted position
    for (int i = t; i < CHUNK; i += 1024) {
        int e = base + i;
        int d = dst[e];
        float2 u = ea[e];
        float u0 = fminf(fmaxf(u.x, 0.f), 1.f);
        float u1 = fminf(fmaxf(u.y, 0.f), 1.f);
        unsigned u0q = __float2uint_rn(u0 * 524287.f);
        unsigned u1q = __float2uint_rn(u1 * 524287.f);
        unsigned w0 = (unsigned)src[e] | ((u0q & 0x7FFFu) << 17);
        unsigned w1 = (u0q >> 15) | (u1q << 4) | ((unsigned)(d & 511) << 23);
        int pos = atomicAdd(&cur[d >> 9], 1);
        rec[pos] = make_uint2(w0, w1);
    }
    __syncthreads();
    // coalesced stream-out: one wave per bucket, round-robin
    int wave = t >> 6, lane = t & 63;      // 16 waves
    for (int bk = wave; bk < NC; bk += 16) {
        int ls = lst[bk];
        int len = cnt[bk];
        int gs = gof[bk];
        for (int i = lane; i < len; i += 64)
            Es[gs + i] = rec[ls + i];
    }
}

// per coarse bucket: LDS histogram -> scan -> rowptr -> LDS-staged scatter -> coalesced write
__global__ __launch_bounds__(1024) void k_fine(const uint2* __restrict__ Es,
                                               const int* __restrict__ cbase,
                                               int* __restrict__ rowptr,
                                               uint2* __restrict__ Ep) {
    extern __shared__ uint2 rec[];         // FCAP records (144KB dynamic)
    __shared__ int cnt[512];
    __shared__ int cur[512];
    __shared__ int sd[512];
    int b = blockIdx.x, t = threadIdx.x;
    int lo = cbase[b], hi = cbase[b + 1];
    int m = hi - lo;
    if (t < 512) cnt[t] = 0;
    __syncthreads();
    for (int i = lo + t; i < hi; i += 1024)
        atomicAdd(&cnt[Es[i].y >> 23], 1);
    __syncthreads();
    if (t < 512) sd[t] = cnt[t];
    __syncthreads();
    for (int off = 1; off < 512; off <<= 1) {
        int x = (t < 512 && t >= off) ? sd[t - off] : 0;
        __syncthreads();
        if (t < 512) sd[t] += x;
        __syncthreads();
    }
    if (t < 512) {
        int excl = sd[t] - cnt[t];
        cur[t] = excl;                     // bucket-relative
        int n = b * 512 + t;
        if (n < N_NODES) rowptr[n] = lo + excl;
    }
    if (b == NC - 1 && t == 0) rowptr[N_NODES] = N_EDGES;
    __syncthreads();
    if (m <= FCAP) {
        for (int i = lo + t; i < hi; i += 1024) {
            uint2 r = Es[i];
            int pos = atomicAdd(&cur[r.y >> 23], 1);
            rec[pos] = r;
        }
        __syncthreads();
        for (int i = t; i < m; i += 1024)   // coalesced stream-out
            Ep[lo + i] = rec[i];
    } else {
        for (int i = lo + t; i < hi; i += 1024) {
            uint2 r = Es[i];
            int pos = atomicAdd(&cur[r.y >> 23], 1);
            Ep[lo + pos] = r;
        }
    }
}

#define DECODE_EDGE(r)                                              \
    int s = r.x & 0x1FFFF;                                          \
    unsigned u0q = (r.x >> 17) | ((r.y & 0xFu) << 15);              \
    unsigned u1q = (r.y >> 4) & 0x7FFFFu;                           \
    float u0 = u0q * (1.f / 524287.f);                              \
    float u1 = u1q * (1.f / 524287.f);                              \
    float nu0 = 1.f - u0, nu1 = 1.f - u1;                           \
    float b0 = nu0 * nu1, b1 = u0 * nu1, b2 = nu0 * u1, b3 = u0 * u1;

// ---------------- layer 1: CIN=3, COUT=8; LDS-staged Ep; 8-way edge split ----------------
#define L1_BODY                                                     \
        DECODE_EDGE(r)                                              \
        uint2 hv = *(const uint2*)(xp + (size_t)s * 4);             \
        float2 p0 = __half22float2(*(__half2*)&hv.x);               \
        float2 p1 = __half22float2(*(__half2*)&hv.y);               \
        float x0 = p0.x, x1 = p0.y, x2 = p1.x;                      \
        z[0] += b0 * x0; z[1]  += b0 * x1; z[2]  += b0 * x2;        \
        z[3] += b1 * x0; z[4]  += b1 * x1; z[5]  += b1 * x2;        \
        z[6] += b2 * x0; z[7]  += b2 * x1; z[8]  += b2 * x2;        \
        z[9] += b3 * x0; z[10] += b3 * x1; z[11] += b3 * x2;

__global__ __launch_bounds__(256) void layer1_kernel(const __half* __restrict__ xp,
                                                     const int* __restrict__ rowptr,
                                                     const uint2* __restrict__ Ep,
                                                     const float* __restrict__ W,
                                                     __half* __restrict__ tout) {
    __shared__ float Wl[96];               // [k][c][d] flat
    __shared__ uint2 recL[ECAP];
    for (int i = threadIdx.x; i < 96; i += 256) Wl[i] = W[i];
    int nb = blockIdx.x * 32;
    int eb = rowptr[nb], ee = rowptr[nb + 32];
    int mm = ee - eb;
    if (mm <= ECAP)
        for (int i = threadIdx.x; i < mm; i += 256) recL[i] = Ep[eb + i];
    __syncthreads();
    int lane8 = threadIdx.x & 7;
    int n = nb + (threadIdx.x >> 3);
    int e0 = rowptr[n], e1 = rowptr[n + 1];
    float z[12];
#pragma unroll
    for (int i = 0; i < 12; ++i) z[i] = 0.f;
    if (mm <= ECAP) {
#pragma unroll 4
        for (int j = e0 - eb + lane8, je = e1 - eb; j < je; j += 8) {
            uint2 r = recL[j];
            L1_BODY
        }
    } else {
#pragma unroll 2
        for (int j = e0 + lane8; j < e1; j += 8) {
            uint2 r = Ep[j];
            L1_BODY
        }
    }
#pragma unroll
    for (int i = 0; i < 12; ++i) {
        z[i] += __shfl_xor(z[i], 4);
        z[i] += __shfl_xor(z[i], 2);
        z[i] += __shfl_xor(z[i], 1);
    }
    float y = 0.f;
#pragma unroll
    for (int kc = 0; kc < 12; ++kc) y += z[kc] * Wl[kc * 8 + lane8];
    float invd = 1.f / fmaxf((float)(e1 - e0), 1.f);
    float v = y * invd;
    v = v > 0.f ? v : expm1f(v);
    tout[(size_t)n * 8 + lane8] = __float2half_rn(v);
}

// ------- layer 2: CIN=8, COUT=16; LDS-staged Ep; packed-f32; BN folded from sums -------
#define L2_BODY                                                     \
        DECODE_EDGE(r)                                              \
        uint2 hv = *(const uint2*)(xin + (size_t)s * 8 + 4 * ch);   \
        float2 p0 = __half22float2(*(__half2*)&hv.x);               \
        float2 p1 = __half22float2(*(__half2*)&hv.y);               \
        f2 x01 = mkf2(p0.x, p0.y), x23 = mkf2(p1.x, p1.y);          \
        S[0] += b0; S[1] += b1; S[2] += b2; S[3] += b3;             \
        f2 bbv;                                                     \
        bbv = mkf2(b0, b0); zf[0] += bbv * x01; zf[1] += bbv * x23; \
        bbv = mkf2(b1, b1); zf[2] += bbv * x01; zf[3] += bbv * x23; \
        bbv = mkf2(b2, b2); zf[4] += bbv * x01; zf[5] += bbv * x23; \
        bbv = mkf2(b3, b3); zf[6] += bbv * x01; zf[7] += bbv * x23;

__global__ __launch_bounds__(256) void layer2_kernel(const __half* __restrict__ xin,
                                                     const float* __restrict__ bns,
                                                     const float* __restrict__ g,
                                                     const float* __restrict__ bb,
                                                     const int* __restrict__ rowptr,
                                                     const uint2* __restrict__ Ep,
                                                     const float* __restrict__ W,
                                                     __half* __restrict__ tout) {
    __shared__ float scA[8], shA[8];
    __shared__ float4 Wl[140];             // f2idx = k*35 + d4p*9 + c   (sc folded)
    __shared__ float shW[64];              // [k][16]
    __shared__ uint2 recL[ECAP];
    int t = threadIdx.x;
    if (t < 8) {
        float mu = bns[t] * (1.f / N_NODES);
        float var = fmaxf(bns[8 + t] * (1.f / N_NODES) - mu * mu, 0.f);
        float s = g[t] * rsqrtf(var + EPS);
        scA[t] = s;
        shA[t] = bb[t] - mu * s;
    }
    int nb = blockIdx.x * 32;
    int eb = rowptr[nb], ee = rowptr[nb + 32];
    int mm = ee - eb;
    if (mm <= ECAP)
        for (int i = t; i < mm; i += 256) recL[i] = Ep[eb + i];
    __syncthreads();
    if (t < 128) {
        int k = t >> 5, d4 = (t >> 3) & 3, c = t & 7;
        float4 w = ((const float4*)W)[(k * 8 + c) * 4 + d4];
        float s = scA[c];
        Wl[k * 35 + d4 * 9 + c] = make_float4(w.x * s, w.y * s, w.z * s, w.w * s);
    } else if (t < 192) {
        int j = t - 128;
        int k = j >> 4, d = j & 15;
        float acc = 0.f;
#pragma unroll
        for (int c = 0; c < 8; ++c) acc += shA[c] * W[(k * 8 + c) * 16 + d];
        shW[j] = acc;
    }
    __syncthreads();

    int lane8 = t & 7;
    int kq = lane8 & 3, h = lane8 >> 2;
    int ch = kq & 1;                       // c-half
    int eo = lane8 >> 1;                   // edge offset 0..3
    int n = nb + (t >> 3);
    int e0 = rowptr[n], e1 = rowptr[n + 1];
    f2 zf[8];
    float S[4];
#pragma unroll
    for (int i = 0; i < 8; ++i) zf[i] = mkf2(0.f, 0.f);
#pragma unroll
    for (int i = 0; i < 4; ++i) S[i] = 0.f;
    if (mm <= ECAP) {
#pragma unroll 4
        for (int j = e0 - eb + eo, je = e1 - eb; j < je; j += 4) {
            uint2 r = recL[j];
            L2_BODY
        }
    } else {
#pragma unroll 2
        for (int j = e0 + eo; j < e1; j += 4) {
            uint2 r = Ep[j];
            L2_BODY
        }
    }
    // edge-subset reduce (masks 4 then 2)
#pragma unroll
    for (int i = 0; i < 8; ++i) {
        zf[i].x += __shfl_xor(zf[i].x, 4); zf[i].y += __shfl_xor(zf[i].y, 4);
        zf[i].x += __shfl_xor(zf[i].x, 2); zf[i].y += __shfl_xor(zf[i].y, 2);
    }
#pragma unroll
    for (int i = 0; i < 4; ++i) { S[i] += __shfl_xor(S[i], 4); S[i] += __shfl_xor(S[i], 2); }

    // packed y-partial: d-half by h, c-half by ch
    int laneW = 18 * h + 4 * ch;
    f2 ya[2], yb[2];
#pragma unroll
    for (int i = 0; i < 2; ++i) { ya[i] = mkf2(0.f, 0.f); yb[i] = mkf2(0.f, 0.f); }
#pragma unroll
    for (int k = 0; k < 4; ++k) {
        float zs[4] = {zf[2 * k].x, zf[2 * k].y, zf[2 * k + 1].x, zf[2 * k + 1].y};
#pragma unroll
        for (int i = 0; i < 4; ++i) {
            f2 zsp = mkf2(zs[i], zs[i]);
            int base = k * 35 + i + laneW;
#pragma unroll
            for (int d4 = 0; d4 < 2; ++d4) {
                float4 w = Wl[base + 9 * d4];
                ya[d4] += zsp * mkf2(w.x, w.y);
                yb[d4] += zsp * mkf2(w.z, w.w);
            }
        }
    }
    float y[8];
#pragma unroll
    for (int d4 = 0; d4 < 2; ++d4) {
        y[4 * d4 + 0] = ya[d4].x; y[4 * d4 + 1] = ya[d4].y;
        y[4 * d4 + 2] = yb[d4].x; y[4 * d4 + 3] = yb[d4].y;
    }
    // mask-1: sum c-halves, keep d-quarter by ch (static select)
    float y1[4];
#pragma unroll
    for (int i = 0; i < 4; ++i) {
        float a = y[i]     + __shfl_xor(y[i],     1);
        float b = y[4 + i] + __shfl_xor(y[4 + i], 1);
        y1[i] = ch ? b : a;
    }
    int qb = (kq >> 1) & 1;
    float f0 = qb ? y1[2] : y1[0];
    float f1 = qb ? y1[3] : y1[1];
    int d = h * 8 + ch * 4 + qb * 2;
    f0 += S[0] * shW[d]     + S[1] * shW[16 + d]     + S[2] * shW[32 + d]     + S[3] * shW[48 + d];
    f1 += S[0] * shW[d + 1] + S[1] * shW[16 + d + 1] + S[2] * shW[32 + d + 1] + S[3] * shW[48 + d + 1];
    float invd = 1.f / fmaxf((float)(e1 - e0), 1.f);
    f0 *= invd; f1 *= invd;
    f0 = f0 > 0.f ? f0 : expm1f(f0);
    f1 = f1 > 0.f ? f1 : expm1f(f1);
    *(__half2*)(tout + (size_t)n * 16 + d) = __floats2half2_rn(f0, f1);
}

// ------- layer 3: CIN=16, COUT=32; LDS-staged Ep; packed-f32; BN folded from sums -------
#define L3_BODY                                                     \
        DECODE_EDGE(r)                                              \
        uint2 hv = *(const uint2*)(xin + (size_t)s * 16 + 4 * kq);  \
        float2 p0 = __half22float2(*(__half2*)&hv.x);               \
        float2 p1 = __half22float2(*(__half2*)&hv.y);               \
        f2 x01 = mkf2(p0.x, p0.y), x23 = mkf2(p1.x, p1.y);          \
        S[0] += b0; S[1] += b1; S[2] += b2; S[3] += b3;             \
        f2 bbv;                                                     \
        bbv = mkf2(b0, b0); zf[0] += bbv * x01; zf[1] += bbv * x23; \
        bbv = mkf2(b1, b1); zf[2] += bbv * x01; zf[3] += bbv * x23; \
        bbv = mkf2(b2, b2); zf[4] += bbv * x01; zf[5] += bbv * x23; \
        bbv = mkf2(b3, b3); zf[6] += bbv * x01; zf[7] += bbv * x23;

__global__ __launch_bounds__(256) void layer3_kernel(const __half* __restrict__ xin,
                                                     const float* __restrict__ bns,
                                                     const float* __restrict__ g,
                                                     const float* __restrict__ bb,
                                                     const int* __restrict__ rowptr,
                                                     const uint2* __restrict__ Ep,
                                                     const float* __restrict__ W,
                                                     __half* __restrict__ tout) {
    __shared__ float scA[16], shA[16];
    __shared__ float4 Wl[580];             // f3 = k*145 + d4p*18 + (d4p>>2) + c + 2*(c>>3)
    __shared__ float shW[128];             // [k][32]
    __shared__ uint2 recL[ECAP];
    int t = threadIdx.x;
    if (t < 16) {
        float mu = bns[t] * (1.f / N_NODES);
        float var = fmaxf(bns[16 + t] * (1.f / N_NODES) - mu * mu, 0.f);
        float s = g[t] * rsqrtf(var + EPS);
        scA[t] = s;
        shA[t] = bb[t] - mu * s;
    }
    int nb = blockIdx.x * 32;
    int eb = rowptr[nb], ee = rowptr[nb + 32];
    int mm = ee - eb;
    if (mm <= ECAP)
        for (int i = t; i < mm; i += 256) recL[i] = Ep[eb + i];
    __syncthreads();
    for (int i = t; i < 512; i += 256) {
        int k = i >> 7, d4 = (i >> 4) & 7, c = i & 15;
        float4 w = ((const float4*)W)[(k * 16 + c) * 8 + d4];
        float s = scA[c];
        Wl[k * 145 + d4 * 18 + (d4 >> 2) + c + 2 * (c >> 3)] =
            make_float4(w.x * s, w.y * s, w.z * s, w.w * s);
    }
    if (t < 128) {
        int k = t >> 5, d = t & 31;
        float acc = 0.f;
#pragma unroll
        for (int c = 0; c < 16; ++c) acc += shA[c] * W[(k * 16 + c) * 32 + d];
        shW[t] = acc;
    }
    __syncthreads();

    int lane8 = t & 7;
    int kq = lane8 & 3, h = lane8 >> 2;
    int n = nb + (t >> 3);
    int e0 = rowptr[n], e1 = rowptr[n + 1];
    f2 zf[8];
    float S[4];
#pragma unroll
    for (int i = 0; i < 8; ++i) zf[i] = mkf2(0.f, 0.f);
#pragma unroll
    for (int i = 0; i < 4; ++i) S[i] = 0.f;
    if (mm <= ECAP) {
#pragma unroll 4
        for (int j = e0 - eb + h, je = e1 - eb; j < je; j += 2) {
            uint2 r = recL[j];
            L3_BODY
        }
    } else {
#pragma unroll 2
        for (int j = e0 + h; j < e1; j += 2) {
            uint2 r = Ep[j];
            L3_BODY
        }
    }
    // h-reduce (edge halves)
#pragma unroll
    for (int i = 0; i < 8; ++i) {
        zf[i].x += __shfl_xor(zf[i].x, 4);
        zf[i].y += __shfl_xor(zf[i].y, 4);
    }
#pragma unroll
    for (int i = 0; i < 4; ++i) S[i] += __shfl_xor(S[i], 4);

    // packed y-partial: d-half by h, c-quarter by kq  (bank-swizzled W reads)
    int laneW = 4 * kq + 2 * (kq >> 1) + 73 * h;
    f2 ya[4], yb[4];
#pragma unroll
    for (int i = 0; i < 4; ++i) { ya[i] = mkf2(0.f, 0.f); yb[i] = mkf2(0.f, 0.f); }
#pragma unroll
    for (int k = 0; k < 4; ++k) {
        float zs[4] = {zf[2 * k].x, zf[2 * k].y, zf[2 * k + 1].x, zf[2 * k + 1].y};
#pragma unroll
        for (int i = 0; i < 4; ++i) {
            f2 zsp = mkf2(zs[i], zs[i]);
            int base = k * 145 + i + laneW;
#pragma unroll
            for (int d4 = 0; d4 < 4; ++d4) {
                float4 w = Wl[base + 18 * d4];
                ya[d4] += zsp * mkf2(w.x, w.y);
                yb[d4] += zsp * mkf2(w.z, w.w);
            }
        }
    }
    float y[16];
#pragma unroll
    for (int d4 = 0; d4 < 4; ++d4) {
        y[4 * d4 + 0] = ya[d4].x; y[4 * d4 + 1] = ya[d4].y;
        y[4 * d4 + 2] = yb[d4].x; y[4 * d4 + 3] = yb[d4].y;
    }
    // select-tree reduce over c-quarters (masks 1 then 2), static indices
    float y1[8];
#pragma unroll
    for (int i = 0; i < 8; ++i) {
        float a = y[i]     + __shfl_xor(y[i],     1);
        float b = y[8 + i] + __shfl_xor(y[8 + i], 1);
        y1[i] = (kq & 1) ? b : a;
    }
    float y2[4];
#pragma unroll
    for (int i = 0; i < 4; ++i) {
        float a = y1[i]     + __shfl_xor(y1[i],     2);
        float b = y1[4 + i] + __shfl_xor(y1[4 + i], 2);
        y2[i] = (kq & 2) ? b : a;
    }
    int d = h * 16 + (kq & 1) * 8 + ((kq >> 1) & 1) * 4;
#pragma unroll
    for (int i = 0; i < 4; ++i)
        y2[i] += S[0] * shW[d + i] + S[1] * shW[32 + d + i] +
                 S[2] * shW[64 + d + i] + S[3] * shW[96 + d + i];
    float invd = 1.f / fmaxf((float)(e1 - e0), 1.f);
#pragma unroll
    for (int i = 0; i < 4; ++i) {
        float v = y2[i] * invd;
        y2[i] = v > 0.f ? v : expm1f(v);
    }
    __half2 h01 = __floats2half2_rn(y2[0], y2[1]);
    __half2 h23 = __floats2half2_rn(y2[2], y2[3]);
    uint2 st;
    st.x = h2u(h01);
    st.y = h2u(h23);
    *(uint2*)(tout + (size_t)n * 32 + d) = st;
}

// ---------------- BN stats (fp16 input, fp32 sums) ----------------
template <int COUT>
__global__ __launch_bounds__(256) void bnstats_kernel(const __half* __restrict__ t,
                                                      float* __restrict__ sums) {
    constexpr int ROWS = 256 / COUT;
    int ch = threadIdx.x % COUT;
    int r = threadIdx.x / COUT;
    float s = 0.f, q = 0.f;
    for (int n = blockIdx.x * ROWS + r; n < N_NODES; n += gridDim.x * ROWS) {
        float v = __half2float(t[(size_t)n * COUT + ch]);
        s += v;
        q += v * v;
    }
    __shared__ float ls[256], lq[256];
    ls[threadIdx.x] = s; lq[threadIdx.x] = q;
    __syncthreads();
    for (int off = 128; off >= COUT; off >>= 1) {
        if (threadIdx.x < off) {
            ls[threadIdx.x] += ls[threadIdx.x + off];
            lq[threadIdx.x] += lq[threadIdx.x + off];
        }
        __syncthreads();
    }
    if (threadIdx.x < COUT) {
        atomicAdd(&sums[ch], ls[threadIdx.x]);
        atomicAdd(&sums[COUT + ch], lq[threadIdx.x]);
    }
}

// ---------------- pooling (batch is sorted) + FC ----------------
__global__ __launch_bounds__(256) void pool_kernel(const __half* __restrict__ t3,
                                                   const int* __restrict__ batch,
                                                   float* __restrict__ pooled) {
    __shared__ float tile[256][33];
    __shared__ int lb[256];
    int n = blockIdx.x * 256 + threadIdx.x;
    int valid = N_NODES - blockIdx.x * 256;
    if (valid > 256) valid = 256;
    if (n < N_NODES) {
        const uint4* r = (const uint4*)(t3 + (size_t)n * 32);
#pragma unroll
        for (int i = 0; i < 4; ++i) {
            uint4 v = r[i];
            float2 a = __half22float2(*(__half2*)&v.x);
            float2 b = __half22float2(*(__half2*)&v.y);
            float2 c = __half22float2(*(__half2*)&v.z);
            float2 d = __half22float2(*(__half2*)&v.w);
            tile[threadIdx.x][8 * i + 0] = a.x;
            tile[threadIdx.x][8 * i + 1] = a.y;
            tile[threadIdx.x][8 * i + 2] = b.x;
            tile[threadIdx.x][8 * i + 3] = b.y;
            tile[threadIdx.x][8 * i + 4] = c.x;
            tile[threadIdx.x][8 * i + 5] = c.y;
            tile[threadIdx.x][8 * i + 6] = d.x;
            tile[threadIdx.x][8 * i + 7] = d.y;
        }
        lb[threadIdx.x] = batch[n];
    }
    __syncthreads();
    if (threadIdx.x < 32) {
        int ch = threadIdx.x;
        float run = 0.f;
        int gp = lb[0];
        for (int r = 0; r < valid; ++r) {
            int g = lb[r];
            if (g != gp) {
                atomicAdd(&pooled[gp * 32 + ch], run);
                run = 0.f;
                gp = g;
            }
            run += tile[r][ch];
        }
        atomicAdd(&pooled[gp * 32 + ch], run);
    }
}

// final: BN3 fold + mean-pool normalize + FC; per-graph counts via binary search (batch sorted)
__global__ void final_kernel(const float* __restrict__ pooled, const int* __restrict__ batch,
                             const float* __restrict__ bns, const float* __restrict__ g,
                             const float* __restrict__ bb, const float* __restrict__ fcw,
                             float* __restrict__ out) {
    __shared__ float sc3[32], sh3[32];
    __shared__ float rcg[64];
    int t = threadIdx.x;
    if (t < 32) {
        float mu = bns[t] * (1.f / N_NODES);
        float var = fmaxf(bns[32 + t] * (1.f / N_NODES) - mu * mu, 0.f);
        float s = g[t] * rsqrtf(var + EPS);
        sc3[t] = s;
        sh3[t] = bb[t] - mu * s;
    } else if (t >= 64 && t < 128) {
        int gr = t - 64;
        int lo0 = 0, hi0 = N_NODES;
        while (lo0 < hi0) { int m = (lo0 + hi0) >> 1; if (batch[m] < gr) lo0 = m + 1; else hi0 = m; }
        int lo1 = lo0, hi1 = N_NODES;
        while (lo1 < hi1) { int m = (lo1 + hi1) >> 1; if (batch[m] < gr + 1) lo1 = m + 1; else hi1 = m; }
        rcg[gr] = 1.f / fmaxf((float)(lo1 - lo0), 1.f);
    }
    __syncthreads();
    int i = t;
    if (i >= N_GRAPHS * 10) return;
    int gi = i / 10, o = i % 10;
    float rc = rcg[gi];
    float acc = 0.f;
#pragma unroll
    for (int d = 0; d < 32; ++d) {
        float pm = sc3[d] * (pooled[gi * 32 + d] * rc) + sh3[d];
        acc += pm * fcw[o * 32 + d];
    }
    out[i] = acc;
}

extern "C" void kernel_launch(void* const* d_in, const int* in_sizes, int n_in,
                              void* d_out, int out_size, void* d_ws, size_t ws_size,
                              hipStream_t stream) {
    const float* x   = (const float*)d_in[0];
    const int*   ei  = (const int*)d_in[1];
    const float* ea  = (const float*)d_in[2];
    const int*   bat = (const int*)d_in[3];
    const float* W1  = (const float*)d_in[4];
    const float* W2  = (const float*)d_in[5];
    const float* W3  = (const float*)d_in[6];
    const float* g1  = (const float*)d_in[7];
    const float* b1  = (const float*)d_in[8];
    const float* g2  = (const float*)d_in[9];
    const float* b2  = (const float*)d_in[10];
    const float* g3  = (const float*)d_in[11];
    const float* b3  = (const float*)d_in[12];
    const float* fcw = (const float*)d_in[13];
    float* out = (float*)d_out;
    char* ws = (char*)d_ws;

    float*  bns1   = (float*)(ws + OFF_BNS1);
    float*  bns2   = (float*)(ws + OFF_BNS2);
    float*  bns3   = (float*)(ws + OFF_BNS3);
    float*  pooled = (float*)(ws + OFF_POOLED);
    int*    cbase  = (int*)(ws + OFF_CBASE);
    int*    btot   = (int*)(ws + OFF_BTOT);
    int*    rowptr = (int*)(ws + OFF_ROWPTR);
    int*    histM  = (int*)(ws + OFF_HISTM);
    uint2*  Es     = (uint2*)(ws + OFF_ES);
    uint2*  Ep     = (uint2*)(ws + OFF_EP);
    __half* xp     = (__half*)(ws + OFF_XP);
    __half* t1     = (__half*)(ws + OFF_T1);
    __half* t2     = (__half*)(ws + OFF_T2);
    __half* t3     = (__half*)(ws + OFF_T3);

    const int* src = ei;
    const int* dst = ei + N_EDGES;

    // allow >64KB dynamic LDS (host-side, idempotent, capture-safe)
    hipFuncSetAttribute((const void*)k_fine,
                        hipFuncAttributeMaxDynamicSharedMemorySize, FCAP * 8);
    hipFuncSetAttribute((const void*)k_part,
                        hipFuncAttributeMaxDynamicSharedMemorySize, CHUNK * 8);

    hipMemsetAsync(ws, 0, ZERO_BYTES, stream);

    xpad_kernel<<<NBLK, 256, 0, stream>>>(x, xp);
    k_hist<<<PBLK, 1024, 0, stream>>>(dst, histM);
    k_scan1<<<NC, 256, 0, stream>>>(histM, btot);
    k_scan2<<<1, 256, 0, stream>>>(btot, cbase);
    k_part<<<PBLK, 1024, CHUNK * 8, stream>>>(src, dst, (const float2*)ea, histM, cbase, Es);
    k_fine<<<NC, 1024, FCAP * 8, stream>>>(Es, cbase, rowptr, Ep);

    layer1_kernel<<<LBLK, 256, 0, stream>>>(xp, rowptr, Ep, W1, t1);
    bnstats_kernel<8><<<256, 256, 0, stream>>>(t1, bns1);

    layer2_kernel<<<LBLK, 256, 0, stream>>>(t1, bns1, g1, b1, rowptr, Ep, W2, t2);
    bnstats_kernel<16><<<256, 256, 0, stream>>>(t2, bns2);

    layer3_kernel<<<LBLK, 256, 0, stream>>>(t2, bns2, g2, b2, rowptr, Ep, W3, t3);
    bnstats_kernel<32><<<256, 256, 0, stream>>>(t3, bns3);

    pool_kernel<<<NBLK, 256, 0, stream>>>(t3, bat, pooled);
    final_kernel<<<1, 640, 0, stream>>>(pooled, bat, bns3, g3, b3, fcw, out);
}